// Round 15
// baseline (516.496 us; speedup 1.0000x reference)
//
#include <hip/hip_runtime.h>

typedef unsigned short u16;
typedef unsigned int u32;
typedef __attribute__((ext_vector_type(4))) float f32x4;
typedef __attribute__((ext_vector_type(8))) short short8;

#if __has_builtin(__builtin_amdgcn_exp2f)
#define EXP2(x) __builtin_amdgcn_exp2f(x)
#else
#define EXP2(x) exp2f(x)
#endif

// 1/sqrt(64) * log2(e): K-proj pre-scale so softmax runs in exp2 domain
#define SCALEK 0.18033688011112042f

__device__ __forceinline__ u16 f2b(float f) {
    unsigned u = __float_as_uint(f);
    u += 0x7fff + ((u >> 16) & 1);
    return (u16)(u >> 16);
}
__device__ __forceinline__ float b2f(u16 v) {
    return __uint_as_float(((unsigned)v) << 16);
}
// XOR swizzle for 128-byte-row LDS tiles
__device__ __forceinline__ int swz(int byteoff) {
    return byteoff ^ (((byteoff >> 7) & 7) << 4);
}
// XOR swizzle for 256-byte-row LDS tiles
__device__ __forceinline__ int swzV(int byteoff) {
    return byteoff ^ (((byteoff >> 8) & 7) << 4);
}
// async global->LDS, 16B per lane; LDS dest must be wave-uniform base
__device__ __forceinline__ void gl16(const u16* g, u16* l) {
    __builtin_amdgcn_global_load_lds(
        (const __attribute__((address_space(1))) unsigned*)(g),
        (__attribute__((address_space(3))) unsigned*)(l), 16, 0, 0);
}
__device__ __forceinline__ u32 cvtpk(float lo, float hi) {
    u32 r;
    asm("v_cvt_pk_bf16_f32 %0, %1, %2" : "=v"(r) : "v"(lo), "v"(hi));
    return r;
}
// (a,b) -> rows: a'=[a0,a2,b0,b2], b'=[a1,a3,b1,b3]  (16-lane rows)
__device__ __forceinline__ void plswap(u32& a, u32& b) {
    asm("v_permlane32_swap_b32 %0, %1" : "+v"(a), "+v"(b));
    asm("v_permlane16_swap_b32 %0, %1" : "+v"(a), "+v"(b));
}
#define MFMA16(a, b, c) __builtin_amdgcn_mfma_f32_16x16x32_bf16((a), (b), (c), 0, 0, 0)

// ---------------------------------------------------------------------------
// Weight packing: W[z][1024][64] -> out rows (voff + h*64 + k), cols d (bf16)
// ---------------------------------------------------------------------------
__global__ __launch_bounds__(256) void pack_wkv_t(const float* __restrict__ W,
                                                  u16* __restrict__ out, int voff) {
    __shared__ float tile[32][33];
    int z = blockIdx.z; int l = z >> 4, h = z & 15;
    const float* ip = W + (size_t)z * 1024 * 64;
    u16* op = out + (size_t)l * 2048 * 1024 + (size_t)(voff + h * 64) * 1024;
    int tx = threadIdx.x & 31, ty = threadIdx.x >> 5;
    int d0 = blockIdx.y * 32, k0 = blockIdx.x * 32;
#pragma unroll
    for (int j = 0; j < 32; j += 8)
        tile[ty + j][tx] = ip[(size_t)(d0 + ty + j) * 64 + k0 + tx];
    __syncthreads();
#pragma unroll
    for (int j = 0; j < 32; j += 8)
        op[(size_t)(k0 + ty + j) * 1024 + d0 + tx] = f2b(tile[tx][ty + j]);
}

__global__ __launch_bounds__(256) void transpose_cvt(const float* __restrict__ in,
                                                     u16* __restrict__ out, int R, int C) {
    __shared__ float tile[32][33];
    const float* ip = in + (size_t)blockIdx.z * R * C;
    u16* op = out + (size_t)blockIdx.z * R * C;
    int tx = threadIdx.x & 31, ty = threadIdx.x >> 5;
    int r0 = blockIdx.y * 32, c0 = blockIdx.x * 32;
#pragma unroll
    for (int j = 0; j < 32; j += 8)
        tile[ty + j][tx] = ip[(size_t)(r0 + ty + j) * C + c0 + tx];
    __syncthreads();
#pragma unroll
    for (int j = 0; j < 32; j += 8)
        op[(size_t)(c0 + ty + j) * R + r0 + tx] = f2b(tile[tx][ty + j]);
}

__global__ __launch_bounds__(256) void cvt_bf16(const float* __restrict__ in,
                                                u16* __restrict__ out, int n) {
    int i = (blockIdx.x * 256 + threadIdx.x) * 4;
    if (i >= n) return;
    float4 v = *(const float4*)&in[i];
    ushort4 o = {f2b(v.x), f2b(v.y), f2b(v.z), f2b(v.w)};
    *(ushort4*)&out[i] = o;
}

// ---------------------------------------------------------------------------
// GEMM: C[M][N] = A[M][1024]bf16 @ B[N][1024]^T (+bias epilogue)
// R10 structure (2-buf barrier loop, BK=64, 2D-region XCD map) + PHASE
// STAGGER: block parity (bid>>3)&1 starts the (order-independent) K loop at
// tile nk/2, wrapping mod nk. Co-resident blocks run ~half-loop out of
// phase, so one block's MFMA window covers the other's vmcnt/barrier drain
// (m114 mechanism needs phase diversity; identical loops phase-lock).
// EPI 0: bf16 out (KV), K cols scaled SCALEK; V^T tile to VTout
// EPI 1: bf16 out, bias + relu     EPI 2: fp32 out, bias
// ---------------------------------------------------------------------------
template <int EPI, int BN>
__global__ __launch_bounds__(256) void gemm_bt(const u16* __restrict__ A,
                                               const u16* __restrict__ B,
                                               const float* __restrict__ bias1,
                                               const float* __restrict__ bias2, int split,
                                               void* __restrict__ Cv,
                                               u16* __restrict__ VTout,
                                               int M, int N, int K) {
    constexpr int NB = BN / 32;
    constexpr int NLB = BN / 32;
    constexpr int L2BN = (BN == 128) ? 7 : 6;
    __shared__ __align__(16) u16 lA[2][128 * 64];
    __shared__ __align__(16) u16 lB[2][BN * 64];
    const int t = threadIdx.x;
    const int lane = t & 63, w = t >> 6;
    const int wr = w >> 1, wc = w & 1;
    const int g = lane >> 4, r = lane & 15;
    // 2D-region XCD decomposition (8x8 blocks per XCD), grid 512 = 16bx x 32by
    const int bid = blockIdx.x;
    const int rgn = bid & 7, idx = bid >> 3;
    const int by = (rgn >> 1) * 8 + (idx >> 3);
    const int bx = (rgn & 1) * 8 + (idx & 7);
    const int m0 = by * 128, n0 = bx * BN;

    const u16* sA[4];
    const u16* sB[NLB];
#pragma unroll
    for (int j = 0; j < 4; ++j) {
        int c = j * 256 + t;
        sA[j] = A + (size_t)(m0 + (c & 127)) * K + (c >> 7) * 8;
    }
#pragma unroll
    for (int j = 0; j < NLB; ++j) {
        int c = j * 256 + t;
        sB[j] = B + (size_t)(n0 + (c & (BN - 1))) * K + (c >> L2BN) * 8;
    }

    f32x4 zero4 = {0.f, 0.f, 0.f, 0.f};
    f32x4 acc[4][NB];
#pragma unroll
    for (int m = 0; m < 4; ++m)
#pragma unroll
        for (int n = 0; n < NB; ++n) acc[m][n] = zero4;

#define GSTAGE(bufi, k0)                                                 \
    do {                                                                 \
        _Pragma("unroll") for (int j = 0; j < 4; ++j)                    \
            gl16(sA[j] + (k0), &lA[bufi][(j * 256 + w * 64) * 8]);       \
        _Pragma("unroll") for (int j = 0; j < NLB; ++j)                  \
            gl16(sB[j] + (k0), &lB[bufi][(j * 256 + w * 64) * 8]);       \
    } while (0)

    const int nk = K >> 6;   // 16
    const int ko = ((bid >> 3) & 1) * (nk >> 1);   // phase stagger
    GSTAGE(0, ko * 64);
    __syncthreads();
    for (int kt = 0; kt < nk; ++kt) {
        const int cur = kt & 1;
        if (kt + 1 < nk) GSTAGE(cur ^ 1, ((kt + 1 + ko) & (nk - 1)) * 64);
#pragma unroll
        for (int ks = 0; ks < 2; ++ks) {
            short8 af[4], bf[NB];
#pragma unroll
            for (int m = 0; m < 4; ++m)
                af[m] = *(const short8*)&lA[cur][((ks * 4 + g) * 128 + wr * 64 + m * 16 + r) * 8];
#pragma unroll
            for (int n = 0; n < NB; ++n)
                bf[n] = *(const short8*)&lB[cur][((ks * 4 + g) * BN + wc * (BN / 2) + n * 16 + r) * 8];
#pragma unroll
            for (int m = 0; m < 4; ++m)
#pragma unroll
                for (int n = 0; n < NB; ++n)
                    acc[m][n] = MFMA16(af[m], bf[n], acc[m][n]);
        }
        __syncthreads();
    }
#undef GSTAGE

#pragma unroll
    for (int m = 0; m < 4; ++m) {
        int row = m0 + wr * 64 + m * 16 + g * 4;
#pragma unroll
        for (int n = 0; n < NB; ++n) {
            int col = n0 + wc * (BN / 2) + n * 16 + r;
            float bv_ = (col < split) ? bias1[col] : bias2[col - split];
            if (EPI == 0) {
                float sc = (col < split) ? SCALEK : 1.0f;
                ushort4 qv;
                qv.x = f2b((acc[m][n][0] + bv_) * sc);
                qv.y = f2b((acc[m][n][1] + bv_) * sc);
                qv.z = f2b((acc[m][n][2] + bv_) * sc);
                qv.w = f2b((acc[m][n][3] + bv_) * sc);
                u16* Cb = (u16*)Cv;
                Cb[(size_t)(row + 0) * N + col] = qv.x;
                Cb[(size_t)(row + 1) * N + col] = qv.y;
                Cb[(size_t)(row + 2) * N + col] = qv.z;
                Cb[(size_t)(row + 3) * N + col] = qv.w;
                if (col >= split) {
                    int d = col - split, b_ = row >> 10, s = row & 1023;
                    *(ushort4*)&VTout[(((size_t)(b_ * 16) + (d >> 6)) * 64 + (d & 63)) * 1024 + s] = qv;
                }
            } else if (EPI == 1) {
                u16* Cb = (u16*)Cv;
#pragma unroll
                for (int i = 0; i < 4; ++i)
                    Cb[(size_t)(row + i) * N + col] = f2b(fmaxf(acc[m][n][i] + bv_, 0.f));
            } else {
#pragma unroll
                for (int i = 0; i < 4; ++i)
                    ((float*)Cv)[(size_t)(row + i) * N + col] = acc[m][n][i] + bv_;
            }
        }
    }
}

// ---------------------------------------------------------------------------
// Flash attention, swapped-QK^T in-register softmax, 8 waves x 16 q-rows.
// KVBLK=128 (R10) + PHASE STAGGER: block parity starts the (order-invariant)
// online-softmax tile loop at tile 4 of 8, wrapping mod 8.
// ---------------------------------------------------------------------------
__global__ __launch_bounds__(512) void attn_kernel(const u16* __restrict__ KV,
                                                   const u16* __restrict__ VT,
                                                   u16* __restrict__ Out) {
    __shared__ __align__(16) u16 kt[2][1024 * 8];   // [key 0..127][d 0..63]
    __shared__ __align__(16) u16 vt[2][1024 * 8];   // [d 0..63][key 0..127]
    const int t = threadIdx.x;
    const int lane = t & 63, w = t >> 6;
    const int g = lane >> 4, r = lane & 15;
    const int d0 = blockIdx.x;
    const int q = d0 >> 3;
    const int bh = (d0 & 7) * 8 + (q >> 3), qb = q & 7;
    const int h = bh & 15, b = bh >> 4;
    const u16* Kbase = KV + (size_t)b * 1024 * 2048 + h * 64;
    const u16* Vbase = Kbase + 1024;
    const u16* VTbase = VT + ((size_t)(b * 16 + h)) * 64 * 1024;

    const int qrow = qb * 128 + w * 16 + r;
    const short8 qf0 = *(const short8*)&Kbase[(size_t)qrow * 2048 + g * 8];
    const short8 qf1 = *(const short8*)&Kbase[(size_t)qrow * 2048 + 32 + g * 8];

    const int krow1 = t >> 3;
    const int kcol = ((((t & 7) * 16) ^ ((krow1 & 7) << 4)) >> 1);
    const u16* Ks1 = Vbase + (size_t)krow1 * 2048 + kcol;
    const u16* Ks2 = Vbase + (size_t)(64 + krow1) * 2048 + kcol;
    const int vrow1 = t >> 4;
    const int vcol = ((((t & 15) * 16) ^ ((vrow1 & 7) << 4)) >> 1);
    const u16* Vs1 = VTbase + (size_t)vrow1 * 1024 + vcol;
    const u16* Vs2 = VTbase + (size_t)(32 + vrow1) * 1024 + vcol;

#define STAGE(bufi, t0)                                              \
    do {                                                             \
        gl16(Ks1 + (size_t)(t0) * 2048, &kt[bufi][(w * 64) * 8]);    \
        gl16(Ks2 + (size_t)(t0) * 2048, &kt[bufi][(512 + w * 64) * 8]); \
        gl16(Vs1 + (t0), &vt[bufi][(w * 64) * 8]);                   \
        gl16(Vs2 + (t0), &vt[bufi][(512 + w * 64) * 8]);             \
    } while (0)

    const int to = ((d0 >> 3) & 1) * 4;   // phase stagger (tile permutation)
    STAGE(0, to * 128);

    float m = -1e30f, l = 0.f;
    f32x4 zero4 = {0.f, 0.f, 0.f, 0.f};
    f32x4 oacc[4];
#pragma unroll
    for (int n = 0; n < 4; ++n) oacc[n] = zero4;
    const int cbase = (lane & 48) | (g << 2);
    __syncthreads();

    for (int tt = 0; tt < 8; ++tt) {
        const int cur = tt & 1;
        if (tt < 7) STAGE(cur ^ 1, ((tt + 1 + to) & 7) * 128);
        const char* kbuf = (const char*)&kt[cur][0];
        const char* vbuf = (const char*)&vt[cur][0];

        f32x4 sfT[8];
#pragma unroll
        for (int n = 0; n < 8; ++n) sfT[n] = zero4;
#pragma unroll
        for (int ks = 0; ks < 2; ++ks) {
            const short8 qf = ks ? qf1 : qf0;
#pragma unroll
            for (int n = 0; n < 8; ++n) {
                short8 kf = *(const short8*)(kbuf + swz((n * 16 + r) * 128 + ks * 64 + g * 16));
                sfT[n] = MFMA16(kf, qf, sfT[n]);
            }
        }
        float rm = -1e30f;
#pragma unroll
        for (int n = 0; n < 8; ++n)
            rm = fmaxf(rm, fmaxf(fmaxf(sfT[n][0], sfT[n][1]), fmaxf(sfT[n][2], sfT[n][3])));
        rm = fmaxf(rm, __shfl_xor(rm, 16, 64));
        rm = fmaxf(rm, __shfl_xor(rm, 32, 64));
        if (!__all(rm <= m + 8.f)) {
            float mn = fmaxf(m, rm);
            float cc = EXP2(m - mn);
            m = mn;
            l *= cc;
#pragma unroll
            for (int i = 0; i < 4; ++i) {
                float ci = __shfl(cc, cbase + i, 64);
#pragma unroll
                for (int n = 0; n < 4; ++n) oacc[n][i] *= ci;
            }
        }
        float rs = 0.f;
#pragma unroll
        for (int n = 0; n < 8; ++n)
#pragma unroll
            for (int i = 0; i < 4; ++i) {
                float p = EXP2(sfT[n][i] - m);
                sfT[n][i] = p;
                rs += p;
            }
        rs += __shfl_xor(rs, 16, 64);
        rs += __shfl_xor(rs, 32, 64);
        l += rs;
        u32 wpk[8][2];
#pragma unroll
        for (int n = 0; n < 8; ++n) {
            wpk[n][0] = cvtpk(sfT[n][0], sfT[n][1]);
            wpk[n][1] = cvtpk(sfT[n][2], sfT[n][3]);
        }
#pragma unroll
        for (int ks = 0; ks < 4; ++ks) {
            u32 a0 = wpk[2 * ks][0], a2 = wpk[2 * ks + 1][0];
            plswap(a0, a2);
            u32 a1 = wpk[2 * ks][1], a3 = wpk[2 * ks + 1][1];
            plswap(a1, a3);
            uint4 av;
            av.x = a0; av.y = a1; av.z = a2; av.w = a3;
            union { uint4 u; short8 s; } uc;
            uc.u = av;
            const short8 af = uc.s;
#pragma unroll
            for (int n = 0; n < 4; ++n) {
                short8 vf = *(const short8*)(vbuf + swzV((n * 16 + r) * 256 + ks * 64 + g * 16));
                oacc[n] = MFMA16(af, vf, oacc[n]);
            }
        }
        __syncthreads();
    }
#undef STAGE

#pragma unroll
    for (int i = 0; i < 4; ++i) {
        float li = 1.f / __shfl(l, cbase + i, 64);
        int orow = b * 1024 + qb * 128 + w * 16 + g * 4 + i;
#pragma unroll
        for (int n = 0; n < 4; ++n)
            Out[(size_t)orow * 1024 + h * 64 + n * 16 + r] = f2b(oacc[n][i] * li);
    }
}

// ---------------------------------------------------------------------------
// Fused residual + LayerNorm, all-bf16 I/O, f32 math (R10 version)
// ---------------------------------------------------------------------------
__global__ __launch_bounds__(256) void ln_kernel(const u16* __restrict__ xin,
                                                 const u16* __restrict__ addin,
                                                 const float* __restrict__ gamma,
                                                 const float* __restrict__ beta,
                                                 u16* __restrict__ xbout) {
    const int row = blockIdx.x, t = threadIdx.x;
    const size_t base = (size_t)row * 1024;
    ushort4 xu = *(const ushort4*)&xin[base + t * 4];
    ushort4 au = *(const ushort4*)&addin[base + t * 4];
    float v0 = b2f(xu.x) + b2f(au.x), v1 = b2f(xu.y) + b2f(au.y);
    float v2 = b2f(xu.z) + b2f(au.z), v3 = b2f(xu.w) + b2f(au.w);
    float s = v0 + v1 + v2 + v3;
    __shared__ float red[4];
    const int lane = t & 63, w = t >> 6;
#pragma unroll
    for (int off = 32; off; off >>= 1) s += __shfl_xor(s, off, 64);
    if (lane == 0) red[w] = s;
    __syncthreads();
    float mean = (red[0] + red[1] + red[2] + red[3]) * (1.f / 1024.f);
    __syncthreads();
    float d0 = v0 - mean, d1 = v1 - mean, d2 = v2 - mean, d3 = v3 - mean;
    float sq = d0 * d0 + d1 * d1 + d2 * d2 + d3 * d3;
#pragma unroll
    for (int off = 32; off; off >>= 1) sq += __shfl_xor(sq, off, 64);
    if (lane == 0) red[w] = sq;
    __syncthreads();
    float var = (red[0] + red[1] + red[2] + red[3]) * (1.f / 1024.f);
    float rstd = rsqrtf(var + 1e-5f);
    float4 gv = *(const float4*)&gamma[t * 4];
    float4 bv = *(const float4*)&beta[t * 4];
    ushort4 o;
    o.x = f2b(d0 * rstd * gv.x + bv.x);
    o.y = f2b(d1 * rstd * gv.y + bv.y);
    o.z = f2b(d2 * rstd * gv.z + bv.z);
    o.w = f2b(d3 * rstd * gv.w + bv.w);
    *(ushort4*)&xbout[base + t * 4] = o;
}

// ---------------------------------------------------------------------------
extern "C" void kernel_launch(void* const* d_in, const int* in_sizes, int n_in,
                              void* d_out, int out_size, void* d_ws, size_t ws_size,
                              hipStream_t stream) {
    const float* x  = (const float*)d_in[0];
    const float* Wk = (const float*)d_in[1];
    const float* bk = (const float*)d_in[2];
    const float* Wv = (const float*)d_in[3];
    const float* bv = (const float*)d_in[4];
    const float* Wl = (const float*)d_in[5];
    const float* bl = (const float*)d_in[6];
    const float* g1 = (const float*)d_in[7];
    const float* b1 = (const float*)d_in[8];
    const float* g2 = (const float*)d_in[9];
    const float* b2 = (const float*)d_in[10];
    const float* Wo = (const float*)d_in[11];
    const float* bo = (const float*)d_in[12];

    char* ws = (char*)d_ws;
    u16* Wkvb = (u16*)ws;  ws += (size_t)4 * 2048 * 1024 * 2;   // 16 MB
    u16* Wlb  = (u16*)ws;  ws += (size_t)4 * 1024 * 1024 * 2;   //  8 MB
    u16* Wob  = (u16*)ws;  ws += (size_t)1024 * 1024 * 2;       //  2 MB
    u16* xb   = (u16*)ws;  ws += (size_t)4096 * 1024 * 2;       //  8 MB
    u16* KVb  = (u16*)ws;  ws += (size_t)4096 * 2048 * 2;       // 16 MB
    u16* VTb  = (u16*)ws;  ws += (size_t)4096 * 1024 * 2;       //  8 MB
    u16* tmpb = (u16*)ws;  ws += (size_t)4096 * 1024 * 2;       //  8 MB

    pack_wkv_t<<<dim3(2, 32, 64), 256, 0, stream>>>(Wk, Wkvb, 0);
    pack_wkv_t<<<dim3(2, 32, 64), 256, 0, stream>>>(Wv, Wkvb, 1024);
    transpose_cvt<<<dim3(32, 32, 4), 256, 0, stream>>>(Wl, Wlb, 1024, 1024);
    transpose_cvt<<<dim3(32, 32, 1), 256, 0, stream>>>(Wo, Wob, 1024, 1024);
    cvt_bf16<<<dim3(4096), 256, 0, stream>>>(x, xb, 4096 * 1024);

    for (int l = 0; l < 4; ++l) {
        // KV: 4096x2048, tile 128x128 BK=64, grid 512 (region-mapped, staggered)
        gemm_bt<0, 128><<<dim3(512), 256, 0, stream>>>(
            xb, Wkvb + (size_t)l * 2048 * 1024, bk + l * 1024, bv + l * 1024, 1024,
            (void*)KVb, VTb, 4096, 2048, 1024);
        attn_kernel<<<dim3(512), 512, 0, stream>>>(KVb, VTb, tmpb);
        ln_kernel<<<dim3(4096), 256, 0, stream>>>(
            xb, tmpb, g1 + l * 1024, b1 + l * 1024, xb);
        // FFN: 4096x1024, tile 128x64 BK=64, grid 512 (region-mapped, staggered)
        gemm_bt<1, 64><<<dim3(512), 256, 0, stream>>>(
            xb, Wlb + (size_t)l * 1024 * 1024, bl + l * 1024, bl + l * 1024, 1024,
            (void*)tmpb, nullptr, 4096, 1024, 1024);
        ln_kernel<<<dim3(4096), 256, 0, stream>>>(
            xb, tmpb, g2 + l * 1024, b2 + l * 1024, xb);
    }
    gemm_bt<2, 64><<<dim3(512), 256, 0, stream>>>(
        xb, Wob, bo, bo, 1024, d_out, nullptr, 4096, 1024, 1024);
}

// Round 16
// 494.168 us; speedup vs baseline: 1.0452x; 1.0452x over previous
//
#include <hip/hip_runtime.h>

typedef unsigned short u16;
typedef unsigned int u32;
typedef __attribute__((ext_vector_type(4))) float f32x4;
typedef __attribute__((ext_vector_type(8))) short short8;

#if __has_builtin(__builtin_amdgcn_exp2f)
#define EXP2(x) __builtin_amdgcn_exp2f(x)
#else
#define EXP2(x) exp2f(x)
#endif

// 1/sqrt(64) * log2(e): K-proj pre-scale so softmax runs in exp2 domain
#define SCALEK 0.18033688011112042f

__device__ __forceinline__ u16 f2b(float f) {
    unsigned u = __float_as_uint(f);
    u += 0x7fff + ((u >> 16) & 1);
    return (u16)(u >> 16);
}
__device__ __forceinline__ float b2f(u16 v) {
    return __uint_as_float(((unsigned)v) << 16);
}
// XOR swizzle for 128-byte-row LDS tiles
__device__ __forceinline__ int swz(int byteoff) {
    return byteoff ^ (((byteoff >> 7) & 7) << 4);
}
// XOR swizzle for 256-byte-row LDS tiles
__device__ __forceinline__ int swzV(int byteoff) {
    return byteoff ^ (((byteoff >> 8) & 7) << 4);
}
// async global->LDS, 16B per lane; LDS dest must be wave-uniform base
__device__ __forceinline__ void gl16(const u16* g, u16* l) {
    __builtin_amdgcn_global_load_lds(
        (const __attribute__((address_space(1))) unsigned*)(g),
        (__attribute__((address_space(3))) unsigned*)(l), 16, 0, 0);
}
__device__ __forceinline__ u32 cvtpk(float lo, float hi) {
    u32 r;
    asm("v_cvt_pk_bf16_f32 %0, %1, %2" : "=v"(r) : "v"(lo), "v"(hi));
    return r;
}
// (a,b) -> rows: a'=[a0,a2,b0,b2], b'=[a1,a3,b1,b3]  (16-lane rows)
__device__ __forceinline__ void plswap(u32& a, u32& b) {
    asm("v_permlane32_swap_b32 %0, %1" : "+v"(a), "+v"(b));
    asm("v_permlane16_swap_b32 %0, %1" : "+v"(a), "+v"(b));
}
#define MFMA16(a, b, c) __builtin_amdgcn_mfma_f32_16x16x32_bf16((a), (b), (c), 0, 0, 0)

// ---------------------------------------------------------------------------
// Weight packing: W[z][1024][64] -> out rows (voff + h*64 + k), cols d (bf16)
// ---------------------------------------------------------------------------
__global__ __launch_bounds__(256) void pack_wkv_t(const float* __restrict__ W,
                                                  u16* __restrict__ out, int voff) {
    __shared__ float tile[32][33];
    int z = blockIdx.z; int l = z >> 4, h = z & 15;
    const float* ip = W + (size_t)z * 1024 * 64;
    u16* op = out + (size_t)l * 2048 * 1024 + (size_t)(voff + h * 64) * 1024;
    int tx = threadIdx.x & 31, ty = threadIdx.x >> 5;
    int d0 = blockIdx.y * 32, k0 = blockIdx.x * 32;
#pragma unroll
    for (int j = 0; j < 32; j += 8)
        tile[ty + j][tx] = ip[(size_t)(d0 + ty + j) * 64 + k0 + tx];
    __syncthreads();
#pragma unroll
    for (int j = 0; j < 32; j += 8)
        op[(size_t)(k0 + ty + j) * 1024 + d0 + tx] = f2b(tile[tx][ty + j]);
}

__global__ __launch_bounds__(256) void transpose_cvt(const float* __restrict__ in,
                                                     u16* __restrict__ out, int R, int C) {
    __shared__ float tile[32][33];
    const float* ip = in + (size_t)blockIdx.z * R * C;
    u16* op = out + (size_t)blockIdx.z * R * C;
    int tx = threadIdx.x & 31, ty = threadIdx.x >> 5;
    int r0 = blockIdx.y * 32, c0 = blockIdx.x * 32;
#pragma unroll
    for (int j = 0; j < 32; j += 8)
        tile[ty + j][tx] = ip[(size_t)(r0 + ty + j) * C + c0 + tx];
    __syncthreads();
#pragma unroll
    for (int j = 0; j < 32; j += 8)
        op[(size_t)(c0 + ty + j) * R + r0 + tx] = f2b(tile[tx][ty + j]);
}

__global__ __launch_bounds__(256) void cvt_bf16(const float* __restrict__ in,
                                                u16* __restrict__ out, int n) {
    int i = (blockIdx.x * 256 + threadIdx.x) * 4;
    if (i >= n) return;
    float4 v = *(const float4*)&in[i];
    ushort4 o = {f2b(v.x), f2b(v.y), f2b(v.z), f2b(v.w)};
    *(ushort4*)&out[i] = o;
}

// ---------------------------------------------------------------------------
// GEMM: C[M][N] = A[M][1024]bf16 @ B[N][1024]^T (+bias epilogue)
// Proven 2-buf barrier loop, BK=64 (R10 best). 2D-region XCD map (8x8
// blocks/XCD): staging loads are local-L2 hits (R8: FETCH halved).
// EPI 0: bf16 out (KV), K cols scaled SCALEK; V^T tile to VTout
// EPI 1: bf16 out, bias + relu     EPI 2: fp32 out, bias
// ---------------------------------------------------------------------------
template <int EPI, int BN>
__global__ __launch_bounds__(256) void gemm_bt(const u16* __restrict__ A,
                                               const u16* __restrict__ B,
                                               const float* __restrict__ bias1,
                                               const float* __restrict__ bias2, int split,
                                               void* __restrict__ Cv,
                                               u16* __restrict__ VTout,
                                               int M, int N, int K) {
    constexpr int NB = BN / 32;            // B frags per wave per ks
    constexpr int NLB = BN / 32;           // B gl16 per thread per stage
    constexpr int L2BN = (BN == 128) ? 7 : 6;
    __shared__ __align__(16) u16 lA[2][128 * 64];
    __shared__ __align__(16) u16 lB[2][BN * 64];
    const int t = threadIdx.x;
    const int lane = t & 63, w = t >> 6;
    const int wr = w >> 1, wc = w & 1;
    const int g = lane >> 4, r = lane & 15;
    // 2D-region XCD decomposition (8x8 blocks per XCD), grid 512 = 16bx x 32by
    const int bid = blockIdx.x;
    const int rgn = bid & 7, idx = bid >> 3;
    const int by = (rgn >> 1) * 8 + (idx >> 3);
    const int bx = (rgn & 1) * 8 + (idx & 7);
    const int m0 = by * 128, n0 = bx * BN;

    // staging chunk c = kc*ROWS + row  (chunk-major LDS [kc][row][8])
    const u16* sA[4];
    const u16* sB[NLB];
#pragma unroll
    for (int j = 0; j < 4; ++j) {
        int c = j * 256 + t;
        sA[j] = A + (size_t)(m0 + (c & 127)) * K + (c >> 7) * 8;
    }
#pragma unroll
    for (int j = 0; j < NLB; ++j) {
        int c = j * 256 + t;
        sB[j] = B + (size_t)(n0 + (c & (BN - 1))) * K + (c >> L2BN) * 8;
    }

    f32x4 zero4 = {0.f, 0.f, 0.f, 0.f};
    f32x4 acc[4][NB];
#pragma unroll
    for (int m = 0; m < 4; ++m)
#pragma unroll
        for (int n = 0; n < NB; ++n) acc[m][n] = zero4;

#define GSTAGE(bufi, k0)                                                 \
    do {                                                                 \
        _Pragma("unroll") for (int j = 0; j < 4; ++j)                    \
            gl16(sA[j] + (k0), &lA[bufi][(j * 256 + w * 64) * 8]);       \
        _Pragma("unroll") for (int j = 0; j < NLB; ++j)                  \
            gl16(sB[j] + (k0), &lB[bufi][(j * 256 + w * 64) * 8]);       \
    } while (0)

    GSTAGE(0, 0);
    __syncthreads();
    const int nk = K >> 6;   // 16
    for (int kt = 0; kt < nk; ++kt) {
        const int cur = kt & 1;
        if (kt + 1 < nk) GSTAGE(cur ^ 1, (kt + 1) * 64);
#pragma unroll
        for (int ks = 0; ks < 2; ++ks) {
            short8 af[4], bf[NB];
#pragma unroll
            for (int m = 0; m < 4; ++m)
                af[m] = *(const short8*)&lA[cur][((ks * 4 + g) * 128 + wr * 64 + m * 16 + r) * 8];
#pragma unroll
            for (int n = 0; n < NB; ++n)
                bf[n] = *(const short8*)&lB[cur][((ks * 4 + g) * BN + wc * (BN / 2) + n * 16 + r) * 8];
#pragma unroll
            for (int m = 0; m < 4; ++m)
#pragma unroll
                for (int n = 0; n < NB; ++n)
                    acc[m][n] = MFMA16(af[m], bf[n], acc[m][n]);
        }
        __syncthreads();
    }
#undef GSTAGE

#pragma unroll
    for (int m = 0; m < 4; ++m) {
        int row = m0 + wr * 64 + m * 16 + g * 4;
#pragma unroll
        for (int n = 0; n < NB; ++n) {
            int col = n0 + wc * (BN / 2) + n * 16 + r;
            float bv_ = (col < split) ? bias1[col] : bias2[col - split];
            if (EPI == 0) {
                float sc = (col < split) ? SCALEK : 1.0f;
                ushort4 qv;
                qv.x = f2b((acc[m][n][0] + bv_) * sc);
                qv.y = f2b((acc[m][n][1] + bv_) * sc);
                qv.z = f2b((acc[m][n][2] + bv_) * sc);
                qv.w = f2b((acc[m][n][3] + bv_) * sc);
                u16* Cb = (u16*)Cv;
                Cb[(size_t)(row + 0) * N + col] = qv.x;
                Cb[(size_t)(row + 1) * N + col] = qv.y;
                Cb[(size_t)(row + 2) * N + col] = qv.z;
                Cb[(size_t)(row + 3) * N + col] = qv.w;
                if (col >= split) {
                    int d = col - split, b_ = row >> 10, s = row & 1023;
                    *(ushort4*)&VTout[(((size_t)(b_ * 16) + (d >> 6)) * 64 + (d & 63)) * 1024 + s] = qv;
                }
            } else if (EPI == 1) {
                u16* Cb = (u16*)Cv;
#pragma unroll
                for (int i = 0; i < 4; ++i)
                    Cb[(size_t)(row + i) * N + col] = f2b(fmaxf(acc[m][n][i] + bv_, 0.f));
            } else {
#pragma unroll
                for (int i = 0; i < 4; ++i)
                    ((float*)Cv)[(size_t)(row + i) * N + col] = acc[m][n][i] + bv_;
            }
        }
    }
}

// ---------------------------------------------------------------------------
// Flash attention, swapped-QK^T in-register softmax, 8 waves x 16 q-rows.
// KVBLK=128: 8 rendezvous, 32 MFMA per barrier. kt rows 128B (swz), vt rows
// 256B (swzV, source pre-swizzled). LDS 64KB. (R10 exact version)
// ---------------------------------------------------------------------------
__global__ __launch_bounds__(512) void attn_kernel(const u16* __restrict__ KV,
                                                   const u16* __restrict__ VT,
                                                   u16* __restrict__ Out) {
    __shared__ __align__(16) u16 kt[2][1024 * 8];   // [key 0..127][d 0..63]
    __shared__ __align__(16) u16 vt[2][1024 * 8];   // [d 0..63][key 0..127]
    const int t = threadIdx.x;
    const int lane = t & 63, w = t >> 6;
    const int g = lane >> 4, r = lane & 15;
    const int d0 = blockIdx.x;
    const int q = d0 >> 3;
    const int bh = (d0 & 7) * 8 + (q >> 3), qb = q & 7;
    const int h = bh & 15, b = bh >> 4;
    const u16* Kbase = KV + (size_t)b * 1024 * 2048 + h * 64;
    const u16* Vbase = Kbase + 1024;
    const u16* VTbase = VT + ((size_t)(b * 16 + h)) * 64 * 1024;

    const int qrow = qb * 128 + w * 16 + r;
    const short8 qf0 = *(const short8*)&Kbase[(size_t)qrow * 2048 + g * 8];
    const short8 qf1 = *(const short8*)&Kbase[(size_t)qrow * 2048 + 32 + g * 8];

    const int krow1 = t >> 3;
    const int kcol = ((((t & 7) * 16) ^ ((krow1 & 7) << 4)) >> 1);
    const u16* Ks1 = Vbase + (size_t)krow1 * 2048 + kcol;
    const u16* Ks2 = Vbase + (size_t)(64 + krow1) * 2048 + kcol;
    const int vrow1 = t >> 4;
    const int vcol = ((((t & 15) * 16) ^ ((vrow1 & 7) << 4)) >> 1);
    const u16* Vs1 = VTbase + (size_t)vrow1 * 1024 + vcol;
    const u16* Vs2 = VTbase + (size_t)(32 + vrow1) * 1024 + vcol;

#define STAGE(bufi, t0)                                              \
    do {                                                             \
        gl16(Ks1 + (size_t)(t0) * 2048, &kt[bufi][(w * 64) * 8]);    \
        gl16(Ks2 + (size_t)(t0) * 2048, &kt[bufi][(512 + w * 64) * 8]); \
        gl16(Vs1 + (t0), &vt[bufi][(w * 64) * 8]);                   \
        gl16(Vs2 + (t0), &vt[bufi][(512 + w * 64) * 8]);             \
    } while (0)

    STAGE(0, 0);

    float m = -1e30f, l = 0.f;
    f32x4 zero4 = {0.f, 0.f, 0.f, 0.f};
    f32x4 oacc[4];
#pragma unroll
    for (int n = 0; n < 4; ++n) oacc[n] = zero4;
    const int cbase = (lane & 48) | (g << 2);
    __syncthreads();

    for (int tt = 0; tt < 8; ++tt) {
        const int cur = tt & 1;
        if (tt < 7) STAGE(cur ^ 1, (tt + 1) * 128);
        const char* kbuf = (const char*)&kt[cur][0];
        const char* vbuf = (const char*)&vt[cur][0];

        f32x4 sfT[8];
#pragma unroll
        for (int n = 0; n < 8; ++n) sfT[n] = zero4;
#pragma unroll
        for (int ks = 0; ks < 2; ++ks) {
            const short8 qf = ks ? qf1 : qf0;
#pragma unroll
            for (int n = 0; n < 8; ++n) {
                short8 kf = *(const short8*)(kbuf + swz((n * 16 + r) * 128 + ks * 64 + g * 16));
                sfT[n] = MFMA16(kf, qf, sfT[n]);
            }
        }
        float rm = -1e30f;
#pragma unroll
        for (int n = 0; n < 8; ++n)
            rm = fmaxf(rm, fmaxf(fmaxf(sfT[n][0], sfT[n][1]), fmaxf(sfT[n][2], sfT[n][3])));
        rm = fmaxf(rm, __shfl_xor(rm, 16, 64));
        rm = fmaxf(rm, __shfl_xor(rm, 32, 64));
        if (!__all(rm <= m + 8.f)) {
            float mn = fmaxf(m, rm);
            float cc = EXP2(m - mn);
            m = mn;
            l *= cc;
#pragma unroll
            for (int i = 0; i < 4; ++i) {
                float ci = __shfl(cc, cbase + i, 64);
#pragma unroll
                for (int n = 0; n < 4; ++n) oacc[n][i] *= ci;
            }
        }
        float rs = 0.f;
#pragma unroll
        for (int n = 0; n < 8; ++n)
#pragma unroll
            for (int i = 0; i < 4; ++i) {
                float p = EXP2(sfT[n][i] - m);
                sfT[n][i] = p;
                rs += p;
            }
        rs += __shfl_xor(rs, 16, 64);
        rs += __shfl_xor(rs, 32, 64);
        l += rs;
        u32 wpk[8][2];
#pragma unroll
        for (int n = 0; n < 8; ++n) {
            wpk[n][0] = cvtpk(sfT[n][0], sfT[n][1]);
            wpk[n][1] = cvtpk(sfT[n][2], sfT[n][3]);
        }
#pragma unroll
        for (int ks = 0; ks < 4; ++ks) {
            u32 a0 = wpk[2 * ks][0], a2 = wpk[2 * ks + 1][0];
            plswap(a0, a2);
            u32 a1 = wpk[2 * ks][1], a3 = wpk[2 * ks + 1][1];
            plswap(a1, a3);
            uint4 av;
            av.x = a0; av.y = a1; av.z = a2; av.w = a3;
            union { uint4 u; short8 s; } uc;
            uc.u = av;
            const short8 af = uc.s;
#pragma unroll
            for (int n = 0; n < 4; ++n) {
                short8 vf = *(const short8*)(vbuf + swzV((n * 16 + r) * 256 + ks * 64 + g * 16));
                oacc[n] = MFMA16(af, vf, oacc[n]);
            }
        }
        __syncthreads();
    }
#undef STAGE

#pragma unroll
    for (int i = 0; i < 4; ++i) {
        float li = 1.f / __shfl(l, cbase + i, 64);
        int orow = b * 1024 + qb * 128 + w * 16 + g * 4 + i;
#pragma unroll
        for (int n = 0; n < 4; ++n)
            Out[(size_t)orow * 1024 + h * 64 + n * 16 + r] = f2b(oacc[n][i] * li);
    }
}

// ---------------------------------------------------------------------------
// Fused residual + LayerNorm, all-bf16 I/O, f32 math (R10 exact version)
// ---------------------------------------------------------------------------
__global__ __launch_bounds__(256) void ln_kernel(const u16* __restrict__ xin,
                                                 const u16* __restrict__ addin,
                                                 const float* __restrict__ gamma,
                                                 const float* __restrict__ beta,
                                                 u16* __restrict__ xbout) {
    const int row = blockIdx.x, t = threadIdx.x;
    const size_t base = (size_t)row * 1024;
    ushort4 xu = *(const ushort4*)&xin[base + t * 4];
    ushort4 au = *(const ushort4*)&addin[base + t * 4];
    float v0 = b2f(xu.x) + b2f(au.x), v1 = b2f(xu.y) + b2f(au.y);
    float v2 = b2f(xu.z) + b2f(au.z), v3 = b2f(xu.w) + b2f(au.w);
    float s = v0 + v1 + v2 + v3;
    __shared__ float red[4];
    const int lane = t & 63, w = t >> 6;
#pragma unroll
    for (int off = 32; off; off >>= 1) s += __shfl_xor(s, off, 64);
    if (lane == 0) red[w] = s;
    __syncthreads();
    float mean = (red[0] + red[1] + red[2] + red[3]) * (1.f / 1024.f);
    __syncthreads();
    float d0 = v0 - mean, d1 = v1 - mean, d2 = v2 - mean, d3 = v3 - mean;
    float sq = d0 * d0 + d1 * d1 + d2 * d2 + d3 * d3;
#pragma unroll
    for (int off = 32; off; off >>= 1) sq += __shfl_xor(sq, off, 64);
    if (lane == 0) red[w] = sq;
    __syncthreads();
    float var = (red[0] + red[1] + red[2] + red[3]) * (1.f / 1024.f);
    float rstd = rsqrtf(var + 1e-5f);
    float4 gv = *(const float4*)&gamma[t * 4];
    float4 bv = *(const float4*)&beta[t * 4];
    ushort4 o;
    o.x = f2b(d0 * rstd * gv.x + bv.x);
    o.y = f2b(d1 * rstd * gv.y + bv.y);
    o.z = f2b(d2 * rstd * gv.z + bv.z);
    o.w = f2b(d3 * rstd * gv.w + bv.w);
    *(ushort4*)&xbout[base + t * 4] = o;
}

// ---------------------------------------------------------------------------
extern "C" void kernel_launch(void* const* d_in, const int* in_sizes, int n_in,
                              void* d_out, int out_size, void* d_ws, size_t ws_size,
                              hipStream_t stream) {
    const float* x  = (const float*)d_in[0];
    const float* Wk = (const float*)d_in[1];
    const float* bk = (const float*)d_in[2];
    const float* Wv = (const float*)d_in[3];
    const float* bv = (const float*)d_in[4];
    const float* Wl = (const float*)d_in[5];
    const float* bl = (const float*)d_in[6];
    const float* g1 = (const float*)d_in[7];
    const float* b1 = (const float*)d_in[8];
    const float* g2 = (const float*)d_in[9];
    const float* b2 = (const float*)d_in[10];
    const float* Wo = (const float*)d_in[11];
    const float* bo = (const float*)d_in[12];

    char* ws = (char*)d_ws;
    u16* Wkvb = (u16*)ws;  ws += (size_t)4 * 2048 * 1024 * 2;   // 16 MB
    u16* Wlb  = (u16*)ws;  ws += (size_t)4 * 1024 * 1024 * 2;   //  8 MB
    u16* Wob  = (u16*)ws;  ws += (size_t)1024 * 1024 * 2;       //  2 MB
    u16* xb   = (u16*)ws;  ws += (size_t)4096 * 1024 * 2;       //  8 MB
    u16* KVb  = (u16*)ws;  ws += (size_t)4096 * 2048 * 2;       // 16 MB
    u16* VTb  = (u16*)ws;  ws += (size_t)4096 * 1024 * 2;       //  8 MB
    u16* tmpb = (u16*)ws;  ws += (size_t)4096 * 1024 * 2;       //  8 MB

    pack_wkv_t<<<dim3(2, 32, 64), 256, 0, stream>>>(Wk, Wkvb, 0);
    pack_wkv_t<<<dim3(2, 32, 64), 256, 0, stream>>>(Wv, Wkvb, 1024);
    transpose_cvt<<<dim3(32, 32, 4), 256, 0, stream>>>(Wl, Wlb, 1024, 1024);
    transpose_cvt<<<dim3(32, 32, 1), 256, 0, stream>>>(Wo, Wob, 1024, 1024);
    cvt_bf16<<<dim3(4096), 256, 0, stream>>>(x, xb, 4096 * 1024);

    for (int l = 0; l < 4; ++l) {
        // KV: 4096x2048, tile 128x128 BK=64, grid 512 (region-mapped)
        gemm_bt<0, 128><<<dim3(512), 256, 0, stream>>>(
            xb, Wkvb + (size_t)l * 2048 * 1024, bk + l * 1024, bv + l * 1024, 1024,
            (void*)KVb, VTb, 4096, 2048, 1024);
        attn_kernel<<<dim3(512), 512, 0, stream>>>(KVb, VTb, tmpb);
        ln_kernel<<<dim3(4096), 256, 0, stream>>>(
            xb, tmpb, g1 + l * 1024, b1 + l * 1024, xb);
        // FFN: 4096x1024, tile 128x64 BK=64, grid 512 (region-mapped)
        gemm_bt<1, 64><<<dim3(512), 256, 0, stream>>>(
            xb, Wlb + (size_t)l * 1024 * 1024, bl + l * 1024, bl + l * 1024, 1024,
            (void*)tmpb, nullptr, 4096, 1024, 1024);
        ln_kernel<<<dim3(4096), 256, 0, stream>>>(
            xb, tmpb, g2 + l * 1024, b2 + l * 1024, xb);
    }
    gemm_bt<2, 64><<<dim3(512), 256, 0, stream>>>(
        xb, Wob, bo, bo, 1024, d_out, nullptr, 4096, 1024, 1024);
}

// Round 17
// 456.204 us; speedup vs baseline: 1.1322x; 1.0832x over previous
//
#include <hip/hip_runtime.h>

typedef unsigned short u16;
typedef unsigned int u32;
typedef signed char i8;
typedef __attribute__((ext_vector_type(4))) float f32x4;
typedef __attribute__((ext_vector_type(4))) int i32x4;
typedef __attribute__((ext_vector_type(8))) short short8;

#if __has_builtin(__builtin_amdgcn_exp2f)
#define EXP2(x) __builtin_amdgcn_exp2f(x)
#else
#define EXP2(x) exp2f(x)
#endif

// 1/sqrt(64) * log2(e): K-proj pre-scale so softmax runs in exp2 domain
#define SCALEK 0.18033688011112042f

__device__ __forceinline__ u16 f2b(float f) {
    unsigned u = __float_as_uint(f);
    u += 0x7fff + ((u >> 16) & 1);
    return (u16)(u >> 16);
}
__device__ __forceinline__ float b2f(u16 v) {
    return __uint_as_float(((unsigned)v) << 16);
}
// XOR swizzle for 128-byte-row LDS tiles
__device__ __forceinline__ int swz(int byteoff) {
    return byteoff ^ (((byteoff >> 7) & 7) << 4);
}
// XOR swizzle for 256-byte-row LDS tiles
__device__ __forceinline__ int swzV(int byteoff) {
    return byteoff ^ (((byteoff >> 8) & 7) << 4);
}
// async global->LDS, 16B per lane; LDS dest must be wave-uniform base
__device__ __forceinline__ void gl16(const void* g, void* l) {
    __builtin_amdgcn_global_load_lds(
        (const __attribute__((address_space(1))) unsigned*)(g),
        (__attribute__((address_space(3))) unsigned*)(l), 16, 0, 0);
}
__device__ __forceinline__ u32 cvtpk(float lo, float hi) {
    u32 r;
    asm("v_cvt_pk_bf16_f32 %0, %1, %2" : "=v"(r) : "v"(lo), "v"(hi));
    return r;
}
// (a,b) -> rows: a'=[a0,a2,b0,b2], b'=[a1,a3,b1,b3]  (16-lane rows)
__device__ __forceinline__ void plswap(u32& a, u32& b) {
    asm("v_permlane32_swap_b32 %0, %1" : "+v"(a), "+v"(b));
    asm("v_permlane16_swap_b32 %0, %1" : "+v"(a), "+v"(b));
}
__device__ __forceinline__ void up8(uint4 u, float* v) {
    v[0] = b2f((u16)u.x); v[1] = b2f((u16)(u.x >> 16));
    v[2] = b2f((u16)u.y); v[3] = b2f((u16)(u.y >> 16));
    v[4] = b2f((u16)u.z); v[5] = b2f((u16)(u.z >> 16));
    v[6] = b2f((u16)u.w); v[7] = b2f((u16)(u.w >> 16));
}
__device__ __forceinline__ int qclamp(float v) {
    int q = __float2int_rn(v);
    return (q > 127) ? 127 : ((q < -127) ? -127 : q);
}
__device__ __forceinline__ u32 pk4(int a, int b, int c, int d) {
    return (u32)(unsigned char)a | ((u32)(unsigned char)b << 8) |
           ((u32)(unsigned char)c << 16) | ((u32)(unsigned char)d << 24);
}
#define MFMA16(a, b, c) __builtin_amdgcn_mfma_f32_16x16x32_bf16((a), (b), (c), 0, 0, 0)
#define MFMAI8(a, b, c) __builtin_amdgcn_mfma_i32_16x16x64_i8((a), (b), (c), 0, 0, 0)

// ---------------------------------------------------------------------------
// Weight packing: W[z][1024][64] -> out rows (voff + h*64 + k), cols d (bf16)
// ---------------------------------------------------------------------------
__global__ __launch_bounds__(256) void pack_wkv_t(const float* __restrict__ W,
                                                  u16* __restrict__ out, int voff) {
    __shared__ float tile[32][33];
    int z = blockIdx.z; int l = z >> 4, h = z & 15;
    const float* ip = W + (size_t)z * 1024 * 64;
    u16* op = out + (size_t)l * 2048 * 1024 + (size_t)(voff + h * 64) * 1024;
    int tx = threadIdx.x & 31, ty = threadIdx.x >> 5;
    int d0 = blockIdx.y * 32, k0 = blockIdx.x * 32;
#pragma unroll
    for (int j = 0; j < 32; j += 8)
        tile[ty + j][tx] = ip[(size_t)(d0 + ty + j) * 64 + k0 + tx];
    __syncthreads();
#pragma unroll
    for (int j = 0; j < 32; j += 8)
        op[(size_t)(k0 + ty + j) * 1024 + d0 + tx] = f2b(tile[tx][ty + j]);
}

__global__ __launch_bounds__(256) void transpose_cvt(const float* __restrict__ in,
                                                     u16* __restrict__ out, int R, int C) {
    __shared__ float tile[32][33];
    const float* ip = in + (size_t)blockIdx.z * R * C;
    u16* op = out + (size_t)blockIdx.z * R * C;
    int tx = threadIdx.x & 31, ty = threadIdx.x >> 5;
    int r0 = blockIdx.y * 32, c0 = blockIdx.x * 32;
#pragma unroll
    for (int j = 0; j < 32; j += 8)
        tile[ty + j][tx] = ip[(size_t)(r0 + ty + j) * C + c0 + tx];
    __syncthreads();
#pragma unroll
    for (int j = 0; j < 32; j += 8)
        op[(size_t)(c0 + ty + j) * R + r0 + tx] = f2b(tile[tx][ty + j]);
}

// ---------------------------------------------------------------------------
// Per-row i8 quantization of a bf16 matrix [Rows][1024] (one wave per row)
// ---------------------------------------------------------------------------
__global__ __launch_bounds__(256) void quant_rows(const u16* __restrict__ in,
                                                  i8* __restrict__ out,
                                                  float* __restrict__ scale) {
    const int t = threadIdx.x, lane = t & 63, w = t >> 6;
    const int row = blockIdx.x * 4 + w;
    const size_t base = (size_t)row * 1024 + lane * 16;
    uint4 v0 = *(const uint4*)&in[base];
    uint4 v1 = *(const uint4*)&in[base + 8];
    float v[16];
    up8(v0, v); up8(v1, v + 8);
    float amax = 0.f;
#pragma unroll
    for (int i = 0; i < 16; ++i) amax = fmaxf(amax, fabsf(v[i]));
#pragma unroll
    for (int off = 32; off; off >>= 1) amax = fmaxf(amax, __shfl_xor(amax, off, 64));
    const float inv = (amax > 0.f) ? 127.f / amax : 0.f;
    u32 q[4];
#pragma unroll
    for (int j = 0; j < 4; ++j)
        q[j] = pk4(qclamp(v[4 * j] * inv), qclamp(v[4 * j + 1] * inv),
                   qclamp(v[4 * j + 2] * inv), qclamp(v[4 * j + 3] * inv));
    uint4 qq = {q[0], q[1], q[2], q[3]};
    *(uint4*)&out[base] = qq;
    if (lane == 0) scale[row] = (amax > 0.f) ? amax / 127.f : 0.f;
}

// ---------------------------------------------------------------------------
// Initial x: f32 [4096][1024] -> bf16 xb + i8 xq + row scale (wave per row)
// ---------------------------------------------------------------------------
__global__ __launch_bounds__(256) void cvtq_row(const float* __restrict__ in,
                                                u16* __restrict__ outb,
                                                i8* __restrict__ outq,
                                                float* __restrict__ scale) {
    const int t = threadIdx.x, lane = t & 63, w = t >> 6;
    const int row = blockIdx.x * 4 + w;
    const size_t base = (size_t)row * 1024 + lane * 16;
    float v[16];
#pragma unroll
    for (int j = 0; j < 4; ++j) {
        float4 f = *(const float4*)&in[base + j * 4];
        v[4 * j] = f.x; v[4 * j + 1] = f.y; v[4 * j + 2] = f.z; v[4 * j + 3] = f.w;
    }
    u32 bw[8];
#pragma unroll
    for (int j = 0; j < 8; ++j) bw[j] = cvtpk(v[2 * j], v[2 * j + 1]);
    uint4 b0 = {bw[0], bw[1], bw[2], bw[3]};
    uint4 b1 = {bw[4], bw[5], bw[6], bw[7]};
    *(uint4*)&outb[base] = b0;
    *(uint4*)&outb[base + 8] = b1;
    float amax = 0.f;
#pragma unroll
    for (int i = 0; i < 16; ++i) amax = fmaxf(amax, fabsf(v[i]));
#pragma unroll
    for (int off = 32; off; off >>= 1) amax = fmaxf(amax, __shfl_xor(amax, off, 64));
    const float inv = (amax > 0.f) ? 127.f / amax : 0.f;
    u32 q[4];
#pragma unroll
    for (int j = 0; j < 4; ++j)
        q[j] = pk4(qclamp(v[4 * j] * inv), qclamp(v[4 * j + 1] * inv),
                   qclamp(v[4 * j + 2] * inv), qclamp(v[4 * j + 3] * inv));
    uint4 qq = {q[0], q[1], q[2], q[3]};
    *(uint4*)&outq[base] = qq;
    if (lane == 0) scale[row] = (amax > 0.f) ? amax / 127.f : 0.f;
}

// ---------------------------------------------------------------------------
// KV projection GEMM in int8: C[4096][2048] = A_i8 @ B_i8^T, exact i32 accum,
// per-row scales sA (x rows) and sB (weight output rows). Tile 128x128,
// BK=128, 4 waves (2x2), chunk-major LDS [kc8][row128][16B] (same geometry
// as the proven bf16 kernel; 0 bank conflicts), 2-buf gl16 staging, 8 iters.
// Staged bytes per block = 256KB (half of bf16) -> VMEM-traffic model
// predicts ~25us. Epilogue: dequant + bias; K cols scaled SCALEK; bf16 KV
// out + V^T tile to VTout. 2D-region XCD map as before.
// ---------------------------------------------------------------------------
__global__ __launch_bounds__(256) void gemm_kv_i8(const i8* __restrict__ A,
                                                  const float* __restrict__ sA,
                                                  const i8* __restrict__ B,
                                                  const float* __restrict__ sB,
                                                  const float* __restrict__ bias1,
                                                  const float* __restrict__ bias2,
                                                  u16* __restrict__ Cb,
                                                  u16* __restrict__ VTout) {
    constexpr int K = 1024, N = 2048;
    __shared__ __align__(16) i8 lA[2][8 * 128 * 16];   // 16 KB per buf
    __shared__ __align__(16) i8 lB[2][8 * 128 * 16];
    const int t = threadIdx.x;
    const int lane = t & 63, w = t >> 6;
    const int wr = w >> 1, wc = w & 1;
    const int g = lane >> 4, r = lane & 15;
    const int bid = blockIdx.x;
    const int rgn = bid & 7, idx = bid >> 3;
    const int by = (rgn >> 1) * 8 + (idx >> 3);
    const int bx = (rgn & 1) * 8 + (idx & 7);
    const int m0 = by * 128, n0 = bx * 128;

    // staging chunk c in [0,1024): kc = c>>7, row = c&127; 16B per chunk
    const i8* sAp[4];
    const i8* sBp[4];
#pragma unroll
    for (int j = 0; j < 4; ++j) {
        int c = j * 256 + t;
        sAp[j] = A + (size_t)(m0 + (c & 127)) * K + (c >> 7) * 16;
        sBp[j] = B + (size_t)(n0 + (c & 127)) * K + (c >> 7) * 16;
    }

    i32x4 acc[4][4];
#pragma unroll
    for (int m = 0; m < 4; ++m)
#pragma unroll
        for (int n = 0; n < 4; ++n) acc[m][n] = (i32x4){0, 0, 0, 0};

#define GSTAGE(bufi, k0)                                                  \
    do {                                                                  \
        _Pragma("unroll") for (int j = 0; j < 4; ++j)                     \
            gl16(sAp[j] + (k0), &lA[bufi][(j * 256 + w * 64) * 16]);      \
        _Pragma("unroll") for (int j = 0; j < 4; ++j)                     \
            gl16(sBp[j] + (k0), &lB[bufi][(j * 256 + w * 64) * 16]);      \
    } while (0)

    GSTAGE(0, 0);
    __syncthreads();
    for (int kt = 0; kt < 8; ++kt) {
        const int cur = kt & 1;
        if (kt + 1 < 8) GSTAGE(cur ^ 1, (kt + 1) * 128);
#pragma unroll
        for (int ks = 0; ks < 2; ++ks) {
            i32x4 af[4], bf[4];
#pragma unroll
            for (int m = 0; m < 4; ++m)
                af[m] = *(const i32x4*)&lA[cur][((ks * 4 + g) * 128 + wr * 64 + m * 16 + r) * 16];
#pragma unroll
            for (int n = 0; n < 4; ++n)
                bf[n] = *(const i32x4*)&lB[cur][((ks * 4 + g) * 128 + wc * 64 + n * 16 + r) * 16];
#pragma unroll
            for (int m = 0; m < 4; ++m)
#pragma unroll
                for (int n = 0; n < 4; ++n)
                    acc[m][n] = MFMAI8(af[m], bf[n], acc[m][n]);
        }
        __syncthreads();
    }
#undef GSTAGE

#pragma unroll
    for (int m = 0; m < 4; ++m) {
        int row = m0 + wr * 64 + m * 16 + g * 4;
        float sx0 = sA[row], sx1 = sA[row + 1], sx2 = sA[row + 2], sx3 = sA[row + 3];
#pragma unroll
        for (int n = 0; n < 4; ++n) {
            int col = n0 + wc * 64 + n * 16 + r;
            float swv = sB[col];
            float bv_ = (col < 1024) ? bias1[col] : bias2[col - 1024];
            float sc = (col < 1024) ? SCALEK : 1.0f;
            ushort4 qv;
            qv.x = f2b(((float)acc[m][n][0] * sx0 * swv + bv_) * sc);
            qv.y = f2b(((float)acc[m][n][1] * sx1 * swv + bv_) * sc);
            qv.z = f2b(((float)acc[m][n][2] * sx2 * swv + bv_) * sc);
            qv.w = f2b(((float)acc[m][n][3] * sx3 * swv + bv_) * sc);
            Cb[(size_t)(row + 0) * N + col] = qv.x;
            Cb[(size_t)(row + 1) * N + col] = qv.y;
            Cb[(size_t)(row + 2) * N + col] = qv.z;
            Cb[(size_t)(row + 3) * N + col] = qv.w;
            if (col >= 1024) {
                int d = col - 1024, b_ = row >> 10, s = row & 1023;
                *(ushort4*)&VTout[(((size_t)(b_ * 16) + (d >> 6)) * 64 + (d & 63)) * 1024 + s] = qv;
            }
        }
    }
}

// ---------------------------------------------------------------------------
// bf16 GEMM (R10 proven): used for FFN + final projection.
// EPI 1: bf16 out, bias + relu     EPI 2: fp32 out, bias
// ---------------------------------------------------------------------------
template <int EPI, int BN>
__global__ __launch_bounds__(256) void gemm_bt(const u16* __restrict__ A,
                                               const u16* __restrict__ B,
                                               const float* __restrict__ bias1,
                                               const float* __restrict__ bias2, int split,
                                               void* __restrict__ Cv,
                                               int M, int N, int K) {
    constexpr int NB = BN / 32;
    constexpr int NLB = BN / 32;
    constexpr int L2BN = (BN == 128) ? 7 : 6;
    __shared__ __align__(16) u16 lA[2][128 * 64];
    __shared__ __align__(16) u16 lB[2][BN * 64];
    const int t = threadIdx.x;
    const int lane = t & 63, w = t >> 6;
    const int wr = w >> 1, wc = w & 1;
    const int g = lane >> 4, r = lane & 15;
    const int bid = blockIdx.x;
    const int rgn = bid & 7, idx = bid >> 3;
    const int by = (rgn >> 1) * 8 + (idx >> 3);
    const int bx = (rgn & 1) * 8 + (idx & 7);
    const int m0 = by * 128, n0 = bx * BN;

    const u16* sA[4];
    const u16* sB[NLB];
#pragma unroll
    for (int j = 0; j < 4; ++j) {
        int c = j * 256 + t;
        sA[j] = A + (size_t)(m0 + (c & 127)) * K + (c >> 7) * 8;
    }
#pragma unroll
    for (int j = 0; j < NLB; ++j) {
        int c = j * 256 + t;
        sB[j] = B + (size_t)(n0 + (c & (BN - 1))) * K + (c >> L2BN) * 8;
    }

    f32x4 zero4 = {0.f, 0.f, 0.f, 0.f};
    f32x4 acc[4][NB];
#pragma unroll
    for (int m = 0; m < 4; ++m)
#pragma unroll
        for (int n = 0; n < NB; ++n) acc[m][n] = zero4;

#define GSTAGE(bufi, k0)                                                 \
    do {                                                                 \
        _Pragma("unroll") for (int j = 0; j < 4; ++j)                    \
            gl16(sA[j] + (k0), &lA[bufi][(j * 256 + w * 64) * 8]);       \
        _Pragma("unroll") for (int j = 0; j < NLB; ++j)                  \
            gl16(sB[j] + (k0), &lB[bufi][(j * 256 + w * 64) * 8]);       \
    } while (0)

    GSTAGE(0, 0);
    __syncthreads();
    const int nk = K >> 6;
    for (int kt = 0; kt < nk; ++kt) {
        const int cur = kt & 1;
        if (kt + 1 < nk) GSTAGE(cur ^ 1, (kt + 1) * 64);
#pragma unroll
        for (int ks = 0; ks < 2; ++ks) {
            short8 af[4], bf[NB];
#pragma unroll
            for (int m = 0; m < 4; ++m)
                af[m] = *(const short8*)&lA[cur][((ks * 4 + g) * 128 + wr * 64 + m * 16 + r) * 8];
#pragma unroll
            for (int n = 0; n < NB; ++n)
                bf[n] = *(const short8*)&lB[cur][((ks * 4 + g) * BN + wc * (BN / 2) + n * 16 + r) * 8];
#pragma unroll
            for (int m = 0; m < 4; ++m)
#pragma unroll
                for (int n = 0; n < NB; ++n)
                    acc[m][n] = MFMA16(af[m], bf[n], acc[m][n]);
        }
        __syncthreads();
    }
#undef GSTAGE

#pragma unroll
    for (int m = 0; m < 4; ++m) {
        int row = m0 + wr * 64 + m * 16 + g * 4;
#pragma unroll
        for (int n = 0; n < NB; ++n) {
            int col = n0 + wc * (BN / 2) + n * 16 + r;
            float bv_ = (col < split) ? bias1[col] : bias2[col - split];
            if (EPI == 1) {
                u16* Cb = (u16*)Cv;
#pragma unroll
                for (int i = 0; i < 4; ++i)
                    Cb[(size_t)(row + i) * N + col] = f2b(fmaxf(acc[m][n][i] + bv_, 0.f));
            } else {
#pragma unroll
                for (int i = 0; i < 4; ++i)
                    ((float*)Cv)[(size_t)(row + i) * N + col] = acc[m][n][i] + bv_;
            }
        }
    }
}

// ---------------------------------------------------------------------------
// Flash attention, swapped-QK^T in-register softmax, 8 waves x 16 q-rows.
// KVBLK=128 (R10 exact version).
// ---------------------------------------------------------------------------
__global__ __launch_bounds__(512) void attn_kernel(const u16* __restrict__ KV,
                                                   const u16* __restrict__ VT,
                                                   u16* __restrict__ Out) {
    __shared__ __align__(16) u16 kt[2][1024 * 8];
    __shared__ __align__(16) u16 vt[2][1024 * 8];
    const int t = threadIdx.x;
    const int lane = t & 63, w = t >> 6;
    const int g = lane >> 4, r = lane & 15;
    const int d0 = blockIdx.x;
    const int q = d0 >> 3;
    const int bh = (d0 & 7) * 8 + (q >> 3), qb = q & 7;
    const int h = bh & 15, b = bh >> 4;
    const u16* Kbase = KV + (size_t)b * 1024 * 2048 + h * 64;
    const u16* Vbase = Kbase + 1024;
    const u16* VTbase = VT + ((size_t)(b * 16 + h)) * 64 * 1024;

    const int qrow = qb * 128 + w * 16 + r;
    const short8 qf0 = *(const short8*)&Kbase[(size_t)qrow * 2048 + g * 8];
    const short8 qf1 = *(const short8*)&Kbase[(size_t)qrow * 2048 + 32 + g * 8];

    const int krow1 = t >> 3;
    const int kcol = ((((t & 7) * 16) ^ ((krow1 & 7) << 4)) >> 1);
    const u16* Ks1 = Vbase + (size_t)krow1 * 2048 + kcol;
    const u16* Ks2 = Vbase + (size_t)(64 + krow1) * 2048 + kcol;
    const int vrow1 = t >> 4;
    const int vcol = ((((t & 15) * 16) ^ ((vrow1 & 7) << 4)) >> 1);
    const u16* Vs1 = VTbase + (size_t)vrow1 * 1024 + vcol;
    const u16* Vs2 = VTbase + (size_t)(32 + vrow1) * 1024 + vcol;

#define STAGE(bufi, t0)                                              \
    do {                                                             \
        gl16(Ks1 + (size_t)(t0) * 2048, &kt[bufi][(w * 64) * 8]);    \
        gl16(Ks2 + (size_t)(t0) * 2048, &kt[bufi][(512 + w * 64) * 8]); \
        gl16(Vs1 + (t0), &vt[bufi][(w * 64) * 8]);                   \
        gl16(Vs2 + (t0), &vt[bufi][(512 + w * 64) * 8]);             \
    } while (0)

    STAGE(0, 0);

    float m = -1e30f, l = 0.f;
    f32x4 zero4 = {0.f, 0.f, 0.f, 0.f};
    f32x4 oacc[4];
#pragma unroll
    for (int n = 0; n < 4; ++n) oacc[n] = zero4;
    const int cbase = (lane & 48) | (g << 2);
    __syncthreads();

    for (int tt = 0; tt < 8; ++tt) {
        const int cur = tt & 1;
        if (tt < 7) STAGE(cur ^ 1, (tt + 1) * 128);
        const char* kbuf = (const char*)&kt[cur][0];
        const char* vbuf = (const char*)&vt[cur][0];

        f32x4 sfT[8];
#pragma unroll
        for (int n = 0; n < 8; ++n) sfT[n] = zero4;
#pragma unroll
        for (int ks = 0; ks < 2; ++ks) {
            const short8 qf = ks ? qf1 : qf0;
#pragma unroll
            for (int n = 0; n < 8; ++n) {
                short8 kf = *(const short8*)(kbuf + swz((n * 16 + r) * 128 + ks * 64 + g * 16));
                sfT[n] = MFMA16(kf, qf, sfT[n]);
            }
        }
        float rm = -1e30f;
#pragma unroll
        for (int n = 0; n < 8; ++n)
            rm = fmaxf(rm, fmaxf(fmaxf(sfT[n][0], sfT[n][1]), fmaxf(sfT[n][2], sfT[n][3])));
        rm = fmaxf(rm, __shfl_xor(rm, 16, 64));
        rm = fmaxf(rm, __shfl_xor(rm, 32, 64));
        if (!__all(rm <= m + 8.f)) {
            float mn = fmaxf(m, rm);
            float cc = EXP2(m - mn);
            m = mn;
            l *= cc;
#pragma unroll
            for (int i = 0; i < 4; ++i) {
                float ci = __shfl(cc, cbase + i, 64);
#pragma unroll
                for (int n = 0; n < 4; ++n) oacc[n][i] *= ci;
            }
        }
        float rs = 0.f;
#pragma unroll
        for (int n = 0; n < 8; ++n)
#pragma unroll
            for (int i = 0; i < 4; ++i) {
                float p = EXP2(sfT[n][i] - m);
                sfT[n][i] = p;
                rs += p;
            }
        rs += __shfl_xor(rs, 16, 64);
        rs += __shfl_xor(rs, 32, 64);
        l += rs;
        u32 wpk[8][2];
#pragma unroll
        for (int n = 0; n < 8; ++n) {
            wpk[n][0] = cvtpk(sfT[n][0], sfT[n][1]);
            wpk[n][1] = cvtpk(sfT[n][2], sfT[n][3]);
        }
#pragma unroll
        for (int ks = 0; ks < 4; ++ks) {
            u32 a0 = wpk[2 * ks][0], a2 = wpk[2 * ks + 1][0];
            plswap(a0, a2);
            u32 a1 = wpk[2 * ks][1], a3 = wpk[2 * ks + 1][1];
            plswap(a1, a3);
            uint4 av;
            av.x = a0; av.y = a1; av.z = a2; av.w = a3;
            union { uint4 u; short8 s; } uc;
            uc.u = av;
            const short8 af = uc.s;
#pragma unroll
            for (int n = 0; n < 4; ++n) {
                short8 vf = *(const short8*)(vbuf + swzV((n * 16 + r) * 256 + ks * 64 + g * 16));
                oacc[n] = MFMA16(af, vf, oacc[n]);
            }
        }
        __syncthreads();
    }
#undef STAGE

#pragma unroll
    for (int i = 0; i < 4; ++i) {
        float li = 1.f / __shfl(l, cbase + i, 64);
        int orow = b * 1024 + qb * 128 + w * 16 + g * 4 + i;
#pragma unroll
        for (int n = 0; n < 4; ++n)
            Out[(size_t)orow * 1024 + h * 64 + n * 16 + r] = f2b(oacc[n][i] * li);
    }
}

// ---------------------------------------------------------------------------
// Fused residual + LayerNorm, all-bf16 I/O, f32 math (R10 structure).
// QOUT=1: additionally emit per-row i8 quantization of the LN output
// (feeds the next layer's i8 KV GEMM).
// ---------------------------------------------------------------------------
template <int QOUT>
__global__ __launch_bounds__(256) void ln_kernel(const u16* __restrict__ xin,
                                                 const u16* __restrict__ addin,
                                                 const float* __restrict__ gamma,
                                                 const float* __restrict__ beta,
                                                 u16* __restrict__ xbout,
                                                 i8* __restrict__ xq,
                                                 float* __restrict__ sx) {
    const int row = blockIdx.x, t = threadIdx.x;
    const size_t base = (size_t)row * 1024;
    ushort4 xu = *(const ushort4*)&xin[base + t * 4];
    ushort4 au = *(const ushort4*)&addin[base + t * 4];
    float v0 = b2f(xu.x) + b2f(au.x), v1 = b2f(xu.y) + b2f(au.y);
    float v2 = b2f(xu.z) + b2f(au.z), v3 = b2f(xu.w) + b2f(au.w);
    float s = v0 + v1 + v2 + v3;
    __shared__ float red[4];
    const int lane = t & 63, w = t >> 6;
#pragma unroll
    for (int off = 32; off; off >>= 1) s += __shfl_xor(s, off, 64);
    if (lane == 0) red[w] = s;
    __syncthreads();
    float mean = (red[0] + red[1] + red[2] + red[3]) * (1.f / 1024.f);
    __syncthreads();
    float d0 = v0 - mean, d1 = v1 - mean, d2 = v2 - mean, d3 = v3 - mean;
    float sq = d0 * d0 + d1 * d1 + d2 * d2 + d3 * d3;
#pragma unroll
    for (int off = 32; off; off >>= 1) sq += __shfl_xor(sq, off, 64);
    if (lane == 0) red[w] = sq;
    __syncthreads();
    float var = (red[0] + red[1] + red[2] + red[3]) * (1.f / 1024.f);
    float rstd = rsqrtf(var + 1e-5f);
    float4 gv = *(const float4*)&gamma[t * 4];
    float4 bv = *(const float4*)&beta[t * 4];
    float o0 = d0 * rstd * gv.x + bv.x;
    float o1 = d1 * rstd * gv.y + bv.y;
    float o2 = d2 * rstd * gv.z + bv.z;
    float o3 = d3 * rstd * gv.w + bv.w;
    ushort4 o;
    o.x = f2b(o0); o.y = f2b(o1); o.z = f2b(o2); o.w = f2b(o3);
    *(ushort4*)&xbout[base + t * 4] = o;
    if (QOUT) {
        float am = fmaxf(fmaxf(fabsf(o0), fabsf(o1)), fmaxf(fabsf(o2), fabsf(o3)));
#pragma unroll
        for (int off = 32; off; off >>= 1) am = fmaxf(am, __shfl_xor(am, off, 64));
        __syncthreads();
        if (lane == 0) red[w] = am;
        __syncthreads();
        float amax = fmaxf(fmaxf(red[0], red[1]), fmaxf(red[2], red[3]));
        float inv = (amax > 0.f) ? 127.f / amax : 0.f;
        u32 qw = pk4(qclamp(o0 * inv), qclamp(o1 * inv), qclamp(o2 * inv), qclamp(o3 * inv));
        *(u32*)&xq[base + t * 4] = qw;
        if (t == 0) sx[row] = (amax > 0.f) ? amax / 127.f : 0.f;
    }
}

// ---------------------------------------------------------------------------
extern "C" void kernel_launch(void* const* d_in, const int* in_sizes, int n_in,
                              void* d_out, int out_size, void* d_ws, size_t ws_size,
                              hipStream_t stream) {
    const float* x  = (const float*)d_in[0];
    const float* Wk = (const float*)d_in[1];
    const float* bk = (const float*)d_in[2];
    const float* Wv = (const float*)d_in[3];
    const float* bv = (const float*)d_in[4];
    const float* Wl = (const float*)d_in[5];
    const float* bl = (const float*)d_in[6];
    const float* g1 = (const float*)d_in[7];
    const float* b1 = (const float*)d_in[8];
    const float* g2 = (const float*)d_in[9];
    const float* b2 = (const float*)d_in[10];
    const float* Wo = (const float*)d_in[11];
    const float* bo = (const float*)d_in[12];

    char* ws = (char*)d_ws;
    u16* Wkvb = (u16*)ws;  ws += (size_t)4 * 2048 * 1024 * 2;   // 16 MB
    u16* Wlb  = (u16*)ws;  ws += (size_t)4 * 1024 * 1024 * 2;   //  8 MB
    u16* Wob  = (u16*)ws;  ws += (size_t)1024 * 1024 * 2;       //  2 MB
    u16* xb   = (u16*)ws;  ws += (size_t)4096 * 1024 * 2;       //  8 MB
    u16* KVb  = (u16*)ws;  ws += (size_t)4096 * 2048 * 2;       // 16 MB
    u16* VTb  = (u16*)ws;  ws += (size_t)4096 * 1024 * 2;       //  8 MB
    u16* tmpb = (u16*)ws;  ws += (size_t)4096 * 1024 * 2;       //  8 MB
    i8*  Wq   = (i8*)ws;   ws += (size_t)4 * 2048 * 1024;       //  8 MB
    i8*  xq   = (i8*)ws;   ws += (size_t)4096 * 1024;           //  4 MB
    float* swf = (float*)ws; ws += (size_t)4 * 2048 * 4;        // 32 KB
    float* sxf = (float*)ws; ws += (size_t)4096 * 4;            // 16 KB

    pack_wkv_t<<<dim3(2, 32, 64), 256, 0, stream>>>(Wk, Wkvb, 0);
    pack_wkv_t<<<dim3(2, 32, 64), 256, 0, stream>>>(Wv, Wkvb, 1024);
    quant_rows<<<dim3(2048), 256, 0, stream>>>(Wkvb, Wq, swf);
    transpose_cvt<<<dim3(32, 32, 4), 256, 0, stream>>>(Wl, Wlb, 1024, 1024);
    transpose_cvt<<<dim3(32, 32, 1), 256, 0, stream>>>(Wo, Wob, 1024, 1024);
    cvtq_row<<<dim3(1024), 256, 0, stream>>>(x, xb, xq, sxf);

    for (int l = 0; l < 4; ++l) {
        // KV: int8, tile 128x128 BK=128, grid 512 (region-mapped)
        gemm_kv_i8<<<dim3(512), 256, 0, stream>>>(
            xq, sxf, Wq + (size_t)l * 2048 * 1024, swf + l * 2048,
            bk + l * 1024, bv + l * 1024, KVb, VTb);
        attn_kernel<<<dim3(512), 512, 0, stream>>>(KVb, VTb, tmpb);
        ln_kernel<0><<<dim3(4096), 256, 0, stream>>>(
            xb, tmpb, g1 + l * 1024, b1 + l * 1024, xb, nullptr, nullptr);
        // FFN: bf16, tile 128x64 BK=64, grid 512 (region-mapped)
        gemm_bt<1, 64><<<dim3(512), 256, 0, stream>>>(
            xb, Wlb + (size_t)l * 1024 * 1024, bl + l * 1024, bl + l * 1024, 1024,
            (void*)tmpb, 4096, 1024, 1024);
        ln_kernel<1><<<dim3(4096), 256, 0, stream>>>(
            xb, tmpb, g2 + l * 1024, b2 + l * 1024, xb, xq, sxf);
    }
    gemm_bt<2, 64><<<dim3(512), 256, 0, stream>>>(
        xb, Wob, bo, bo, 1024, d_out, 4096, 1024, 1024);
}

// Round 18
// 422.174 us; speedup vs baseline: 1.2234x; 1.0806x over previous
//
#include <hip/hip_runtime.h>

typedef unsigned short u16;
typedef unsigned int u32;
typedef signed char i8;
typedef __attribute__((ext_vector_type(4))) float f32x4;
typedef __attribute__((ext_vector_type(4))) int i32x4;
typedef __attribute__((ext_vector_type(8))) short short8;

#if __has_builtin(__builtin_amdgcn_exp2f)
#define EXP2(x) __builtin_amdgcn_exp2f(x)
#else
#define EXP2(x) exp2f(x)
#endif

// 1/sqrt(64) * log2(e): K-proj pre-scale so softmax runs in exp2 domain
#define SCALEK 0.18033688011112042f

__device__ __forceinline__ u16 f2b(float f) {
    unsigned u = __float_as_uint(f);
    u += 0x7fff + ((u >> 16) & 1);
    return (u16)(u >> 16);
}
__device__ __forceinline__ float b2f(u16 v) {
    return __uint_as_float(((unsigned)v) << 16);
}
// XOR swizzle for 128-byte-row LDS tiles
__device__ __forceinline__ int swz(int byteoff) {
    return byteoff ^ (((byteoff >> 7) & 7) << 4);
}
// XOR swizzle for 256-byte-row LDS tiles
__device__ __forceinline__ int swzV(int byteoff) {
    return byteoff ^ (((byteoff >> 8) & 7) << 4);
}
// async global->LDS, 16B per lane; LDS dest must be wave-uniform base
__device__ __forceinline__ void gl16(const void* g, void* l) {
    __builtin_amdgcn_global_load_lds(
        (const __attribute__((address_space(1))) unsigned*)(g),
        (__attribute__((address_space(3))) unsigned*)(l), 16, 0, 0);
}
__device__ __forceinline__ u32 cvtpk(float lo, float hi) {
    u32 r;
    asm("v_cvt_pk_bf16_f32 %0, %1, %2" : "=v"(r) : "v"(lo), "v"(hi));
    return r;
}
// (a,b) -> rows: a'=[a0,a2,b0,b2], b'=[a1,a3,b1,b3]  (16-lane rows)
__device__ __forceinline__ void plswap(u32& a, u32& b) {
    asm("v_permlane32_swap_b32 %0, %1" : "+v"(a), "+v"(b));
    asm("v_permlane16_swap_b32 %0, %1" : "+v"(a), "+v"(b));
}
__device__ __forceinline__ void up8(uint4 u, float* v) {
    v[0] = b2f((u16)u.x); v[1] = b2f((u16)(u.x >> 16));
    v[2] = b2f((u16)u.y); v[3] = b2f((u16)(u.y >> 16));
    v[4] = b2f((u16)u.z); v[5] = b2f((u16)(u.z >> 16));
    v[6] = b2f((u16)u.w); v[7] = b2f((u16)(u.w >> 16));
}
__device__ __forceinline__ int qclamp(float v) {
    int q = __float2int_rn(v);
    return (q > 127) ? 127 : ((q < -127) ? -127 : q);
}
__device__ __forceinline__ u32 pk4(int a, int b, int c, int d) {
    return (u32)(unsigned char)a | ((u32)(unsigned char)b << 8) |
           ((u32)(unsigned char)c << 16) | ((u32)(unsigned char)d << 24);
}
#define MFMA16(a, b, c) __builtin_amdgcn_mfma_f32_16x16x32_bf16((a), (b), (c), 0, 0, 0)
#define MFMAI8(a, b, c) __builtin_amdgcn_mfma_i32_16x16x64_i8((a), (b), (c), 0, 0, 0)

// ---------------------------------------------------------------------------
// Weight packing: W[z][1024][64] -> out rows (voff + h*64 + k), cols d (bf16)
// ---------------------------------------------------------------------------
__global__ __launch_bounds__(256) void pack_wkv_t(const float* __restrict__ W,
                                                  u16* __restrict__ out, int voff) {
    __shared__ float tile[32][33];
    int z = blockIdx.z; int l = z >> 4, h = z & 15;
    const float* ip = W + (size_t)z * 1024 * 64;
    u16* op = out + (size_t)l * 2048 * 1024 + (size_t)(voff + h * 64) * 1024;
    int tx = threadIdx.x & 31, ty = threadIdx.x >> 5;
    int d0 = blockIdx.y * 32, k0 = blockIdx.x * 32;
#pragma unroll
    for (int j = 0; j < 32; j += 8)
        tile[ty + j][tx] = ip[(size_t)(d0 + ty + j) * 64 + k0 + tx];
    __syncthreads();
#pragma unroll
    for (int j = 0; j < 32; j += 8)
        op[(size_t)(k0 + ty + j) * 1024 + d0 + tx] = f2b(tile[tx][ty + j]);
}

__global__ __launch_bounds__(256) void transpose_cvt(const float* __restrict__ in,
                                                     u16* __restrict__ out, int R, int C) {
    __shared__ float tile[32][33];
    const float* ip = in + (size_t)blockIdx.z * R * C;
    u16* op = out + (size_t)blockIdx.z * R * C;
    int tx = threadIdx.x & 31, ty = threadIdx.x >> 5;
    int r0 = blockIdx.y * 32, c0 = blockIdx.x * 32;
#pragma unroll
    for (int j = 0; j < 32; j += 8)
        tile[ty + j][tx] = ip[(size_t)(r0 + ty + j) * C + c0 + tx];
    __syncthreads();
#pragma unroll
    for (int j = 0; j < 32; j += 8)
        op[(size_t)(c0 + ty + j) * R + r0 + tx] = f2b(tile[tx][ty + j]);
}

// ---------------------------------------------------------------------------
// Per-row i8 quantization of a bf16 matrix [Rows][1024] (one wave per row)
// ---------------------------------------------------------------------------
__global__ __launch_bounds__(256) void quant_rows(const u16* __restrict__ in,
                                                  i8* __restrict__ out,
                                                  float* __restrict__ scale) {
    const int t = threadIdx.x, lane = t & 63, w = t >> 6;
    const int row = blockIdx.x * 4 + w;
    const size_t base = (size_t)row * 1024 + lane * 16;
    uint4 v0 = *(const uint4*)&in[base];
    uint4 v1 = *(const uint4*)&in[base + 8];
    float v[16];
    up8(v0, v); up8(v1, v + 8);
    float amax = 0.f;
#pragma unroll
    for (int i = 0; i < 16; ++i) amax = fmaxf(amax, fabsf(v[i]));
#pragma unroll
    for (int off = 32; off; off >>= 1) amax = fmaxf(amax, __shfl_xor(amax, off, 64));
    const float inv = (amax > 0.f) ? 127.f / amax : 0.f;
    u32 q[4];
#pragma unroll
    for (int j = 0; j < 4; ++j)
        q[j] = pk4(qclamp(v[4 * j] * inv), qclamp(v[4 * j + 1] * inv),
                   qclamp(v[4 * j + 2] * inv), qclamp(v[4 * j + 3] * inv));
    uint4 qq = {q[0], q[1], q[2], q[3]};
    *(uint4*)&out[base] = qq;
    if (lane == 0) scale[row] = (amax > 0.f) ? amax / 127.f : 0.f;
}

// ---------------------------------------------------------------------------
// Initial x: f32 [4096][1024] -> bf16 xb + i8 xq + row scale (wave per row)
// ---------------------------------------------------------------------------
__global__ __launch_bounds__(256) void cvtq_row(const float* __restrict__ in,
                                                u16* __restrict__ outb,
                                                i8* __restrict__ outq,
                                                float* __restrict__ scale) {
    const int t = threadIdx.x, lane = t & 63, w = t >> 6;
    const int row = blockIdx.x * 4 + w;
    const size_t base = (size_t)row * 1024 + lane * 16;
    float v[16];
#pragma unroll
    for (int j = 0; j < 4; ++j) {
        float4 f = *(const float4*)&in[base + j * 4];
        v[4 * j] = f.x; v[4 * j + 1] = f.y; v[4 * j + 2] = f.z; v[4 * j + 3] = f.w;
    }
    u32 bw[8];
#pragma unroll
    for (int j = 0; j < 8; ++j) bw[j] = cvtpk(v[2 * j], v[2 * j + 1]);
    uint4 b0 = {bw[0], bw[1], bw[2], bw[3]};
    uint4 b1 = {bw[4], bw[5], bw[6], bw[7]};
    *(uint4*)&outb[base] = b0;
    *(uint4*)&outb[base + 8] = b1;
    float amax = 0.f;
#pragma unroll
    for (int i = 0; i < 16; ++i) amax = fmaxf(amax, fabsf(v[i]));
#pragma unroll
    for (int off = 32; off; off >>= 1) amax = fmaxf(amax, __shfl_xor(amax, off, 64));
    const float inv = (amax > 0.f) ? 127.f / amax : 0.f;
    u32 q[4];
#pragma unroll
    for (int j = 0; j < 4; ++j)
        q[j] = pk4(qclamp(v[4 * j] * inv), qclamp(v[4 * j + 1] * inv),
                   qclamp(v[4 * j + 2] * inv), qclamp(v[4 * j + 3] * inv));
    uint4 qq = {q[0], q[1], q[2], q[3]};
    *(uint4*)&outq[base] = qq;
    if (lane == 0) scale[row] = (amax > 0.f) ? amax / 127.f : 0.f;
}

// ---------------------------------------------------------------------------
// KV projection GEMM in int8 (R17 proven): C[4096][2048] = A_i8 @ B_i8^T,
// i32 accum, per-row scales. Tile 128x128, BK=128, 2-buf, region map.
// ---------------------------------------------------------------------------
__global__ __launch_bounds__(256) void gemm_kv_i8(const i8* __restrict__ A,
                                                  const float* __restrict__ sA,
                                                  const i8* __restrict__ B,
                                                  const float* __restrict__ sB,
                                                  const float* __restrict__ bias1,
                                                  const float* __restrict__ bias2,
                                                  u16* __restrict__ Cb,
                                                  u16* __restrict__ VTout) {
    constexpr int K = 1024, N = 2048;
    __shared__ __align__(16) i8 lA[2][8 * 128 * 16];
    __shared__ __align__(16) i8 lB[2][8 * 128 * 16];
    const int t = threadIdx.x;
    const int lane = t & 63, w = t >> 6;
    const int wr = w >> 1, wc = w & 1;
    const int g = lane >> 4, r = lane & 15;
    const int bid = blockIdx.x;
    const int rgn = bid & 7, idx = bid >> 3;
    const int by = (rgn >> 1) * 8 + (idx >> 3);
    const int bx = (rgn & 1) * 8 + (idx & 7);
    const int m0 = by * 128, n0 = bx * 128;

    const i8* sAp[4];
    const i8* sBp[4];
#pragma unroll
    for (int j = 0; j < 4; ++j) {
        int c = j * 256 + t;
        sAp[j] = A + (size_t)(m0 + (c & 127)) * K + (c >> 7) * 16;
        sBp[j] = B + (size_t)(n0 + (c & 127)) * K + (c >> 7) * 16;
    }

    i32x4 acc[4][4];
#pragma unroll
    for (int m = 0; m < 4; ++m)
#pragma unroll
        for (int n = 0; n < 4; ++n) acc[m][n] = (i32x4){0, 0, 0, 0};

#define GSTAGE(bufi, k0)                                                  \
    do {                                                                  \
        _Pragma("unroll") for (int j = 0; j < 4; ++j)                     \
            gl16(sAp[j] + (k0), &lA[bufi][(j * 256 + w * 64) * 16]);      \
        _Pragma("unroll") for (int j = 0; j < 4; ++j)                     \
            gl16(sBp[j] + (k0), &lB[bufi][(j * 256 + w * 64) * 16]);      \
    } while (0)

    GSTAGE(0, 0);
    __syncthreads();
    for (int kt = 0; kt < 8; ++kt) {
        const int cur = kt & 1;
        if (kt + 1 < 8) GSTAGE(cur ^ 1, (kt + 1) * 128);
#pragma unroll
        for (int ks = 0; ks < 2; ++ks) {
            i32x4 af[4], bf[4];
#pragma unroll
            for (int m = 0; m < 4; ++m)
                af[m] = *(const i32x4*)&lA[cur][((ks * 4 + g) * 128 + wr * 64 + m * 16 + r) * 16];
#pragma unroll
            for (int n = 0; n < 4; ++n)
                bf[n] = *(const i32x4*)&lB[cur][((ks * 4 + g) * 128 + wc * 64 + n * 16 + r) * 16];
#pragma unroll
            for (int m = 0; m < 4; ++m)
#pragma unroll
                for (int n = 0; n < 4; ++n)
                    acc[m][n] = MFMAI8(af[m], bf[n], acc[m][n]);
        }
        __syncthreads();
    }
#undef GSTAGE

#pragma unroll
    for (int m = 0; m < 4; ++m) {
        int row = m0 + wr * 64 + m * 16 + g * 4;
        float sx0 = sA[row], sx1 = sA[row + 1], sx2 = sA[row + 2], sx3 = sA[row + 3];
#pragma unroll
        for (int n = 0; n < 4; ++n) {
            int col = n0 + wc * 64 + n * 16 + r;
            float swv = sB[col];
            float bv_ = (col < 1024) ? bias1[col] : bias2[col - 1024];
            float sc = (col < 1024) ? SCALEK : 1.0f;
            ushort4 qv;
            qv.x = f2b(((float)acc[m][n][0] * sx0 * swv + bv_) * sc);
            qv.y = f2b(((float)acc[m][n][1] * sx1 * swv + bv_) * sc);
            qv.z = f2b(((float)acc[m][n][2] * sx2 * swv + bv_) * sc);
            qv.w = f2b(((float)acc[m][n][3] * sx3 * swv + bv_) * sc);
            Cb[(size_t)(row + 0) * N + col] = qv.x;
            Cb[(size_t)(row + 1) * N + col] = qv.y;
            Cb[(size_t)(row + 2) * N + col] = qv.z;
            Cb[(size_t)(row + 3) * N + col] = qv.w;
            if (col >= 1024) {
                int d = col - 1024, b_ = row >> 10, s = row & 1023;
                *(ushort4*)&VTout[(((size_t)(b_ * 16) + (d >> 6)) * 64 + (d & 63)) * 1024 + s] = qv;
            }
        }
    }
}

// ---------------------------------------------------------------------------
// Generic int8 GEMM, tile 128 x 64, BK=128, grid 512 (region map).
// C[4096][1024] = A_i8[4096][1024] @ B_i8[1024][1024]^T, dequant epilogue.
// EPI 1: bf16 out, bias + relu     EPI 2: fp32 out, bias
// ---------------------------------------------------------------------------
template <int EPI>
__global__ __launch_bounds__(256) void gemm_i8(const i8* __restrict__ A,
                                               const float* __restrict__ sA,
                                               const i8* __restrict__ B,
                                               const float* __restrict__ sB,
                                               const float* __restrict__ bias,
                                               void* __restrict__ Cv) {
    constexpr int K = 1024, N = 1024;
    __shared__ __align__(16) i8 lA[2][8 * 128 * 16];   // 16 KB
    __shared__ __align__(16) i8 lB[2][8 * 64 * 16];    //  8 KB
    const int t = threadIdx.x;
    const int lane = t & 63, w = t >> 6;
    const int wr = w >> 1, wc = w & 1;
    const int g = lane >> 4, r = lane & 15;
    const int bid = blockIdx.x;
    const int rgn = bid & 7, idx = bid >> 3;
    const int by = (rgn >> 1) * 8 + (idx >> 3);
    const int bx = (rgn & 1) * 8 + (idx & 7);
    const int m0 = by * 128, n0 = bx * 64;

    const i8* sAp[4];
    const i8* sBp[2];
#pragma unroll
    for (int j = 0; j < 4; ++j) {
        int c = j * 256 + t;
        sAp[j] = A + (size_t)(m0 + (c & 127)) * K + (c >> 7) * 16;
    }
#pragma unroll
    for (int j = 0; j < 2; ++j) {
        int c = j * 256 + t;
        sBp[j] = B + (size_t)(n0 + (c & 63)) * K + (c >> 6) * 16;
    }

    i32x4 acc[4][2];
#pragma unroll
    for (int m = 0; m < 4; ++m)
#pragma unroll
        for (int n = 0; n < 2; ++n) acc[m][n] = (i32x4){0, 0, 0, 0};

#define GSTAGE(bufi, k0)                                                  \
    do {                                                                  \
        _Pragma("unroll") for (int j = 0; j < 4; ++j)                     \
            gl16(sAp[j] + (k0), &lA[bufi][(j * 256 + w * 64) * 16]);      \
        _Pragma("unroll") for (int j = 0; j < 2; ++j)                     \
            gl16(sBp[j] + (k0), &lB[bufi][(j * 256 + w * 64) * 16]);      \
    } while (0)

    GSTAGE(0, 0);
    __syncthreads();
    for (int kt = 0; kt < 8; ++kt) {
        const int cur = kt & 1;
        if (kt + 1 < 8) GSTAGE(cur ^ 1, (kt + 1) * 128);
#pragma unroll
        for (int ks = 0; ks < 2; ++ks) {
            i32x4 af[4], bf[2];
#pragma unroll
            for (int m = 0; m < 4; ++m)
                af[m] = *(const i32x4*)&lA[cur][((ks * 4 + g) * 128 + wr * 64 + m * 16 + r) * 16];
#pragma unroll
            for (int n = 0; n < 2; ++n)
                bf[n] = *(const i32x4*)&lB[cur][((ks * 4 + g) * 64 + wc * 32 + n * 16 + r) * 16];
#pragma unroll
            for (int m = 0; m < 4; ++m)
#pragma unroll
                for (int n = 0; n < 2; ++n)
                    acc[m][n] = MFMAI8(af[m], bf[n], acc[m][n]);
        }
        __syncthreads();
    }
#undef GSTAGE

#pragma unroll
    for (int m = 0; m < 4; ++m) {
        int row = m0 + wr * 64 + m * 16 + g * 4;
        float sx0 = sA[row], sx1 = sA[row + 1], sx2 = sA[row + 2], sx3 = sA[row + 3];
#pragma unroll
        for (int n = 0; n < 2; ++n) {
            int col = n0 + wc * 32 + n * 16 + r;
            float swv = sB[col];
            float bv_ = bias[col];
            float v0 = (float)acc[m][n][0] * sx0 * swv + bv_;
            float v1 = (float)acc[m][n][1] * sx1 * swv + bv_;
            float v2 = (float)acc[m][n][2] * sx2 * swv + bv_;
            float v3 = (float)acc[m][n][3] * sx3 * swv + bv_;
            if (EPI == 1) {
                u16* Cb = (u16*)Cv;
                Cb[(size_t)(row + 0) * N + col] = f2b(fmaxf(v0, 0.f));
                Cb[(size_t)(row + 1) * N + col] = f2b(fmaxf(v1, 0.f));
                Cb[(size_t)(row + 2) * N + col] = f2b(fmaxf(v2, 0.f));
                Cb[(size_t)(row + 3) * N + col] = f2b(fmaxf(v3, 0.f));
            } else {
                float* Cf = (float*)Cv;
                Cf[(size_t)(row + 0) * N + col] = v0;
                Cf[(size_t)(row + 1) * N + col] = v1;
                Cf[(size_t)(row + 2) * N + col] = v2;
                Cf[(size_t)(row + 3) * N + col] = v3;
            }
        }
    }
}

// ---------------------------------------------------------------------------
// Flash attention, swapped-QK^T in-register softmax, 8 waves x 16 q-rows.
// KVBLK=128 (R10 exact version).
// ---------------------------------------------------------------------------
__global__ __launch_bounds__(512) void attn_kernel(const u16* __restrict__ KV,
                                                   const u16* __restrict__ VT,
                                                   u16* __restrict__ Out) {
    __shared__ __align__(16) u16 kt[2][1024 * 8];
    __shared__ __align__(16) u16 vt[2][1024 * 8];
    const int t = threadIdx.x;
    const int lane = t & 63, w = t >> 6;
    const int g = lane >> 4, r = lane & 15;
    const int d0 = blockIdx.x;
    const int q = d0 >> 3;
    const int bh = (d0 & 7) * 8 + (q >> 3), qb = q & 7;
    const int h = bh & 15, b = bh >> 4;
    const u16* Kbase = KV + (size_t)b * 1024 * 2048 + h * 64;
    const u16* Vbase = Kbase + 1024;
    const u16* VTbase = VT + ((size_t)(b * 16 + h)) * 64 * 1024;

    const int qrow = qb * 128 + w * 16 + r;
    const short8 qf0 = *(const short8*)&Kbase[(size_t)qrow * 2048 + g * 8];
    const short8 qf1 = *(const short8*)&Kbase[(size_t)qrow * 2048 + 32 + g * 8];

    const int krow1 = t >> 3;
    const int kcol = ((((t & 7) * 16) ^ ((krow1 & 7) << 4)) >> 1);
    const u16* Ks1 = Vbase + (size_t)krow1 * 2048 + kcol;
    const u16* Ks2 = Vbase + (size_t)(64 + krow1) * 2048 + kcol;
    const int vrow1 = t >> 4;
    const int vcol = ((((t & 15) * 16) ^ ((vrow1 & 7) << 4)) >> 1);
    const u16* Vs1 = VTbase + (size_t)vrow1 * 1024 + vcol;
    const u16* Vs2 = VTbase + (size_t)(32 + vrow1) * 1024 + vcol;

#define STAGE(bufi, t0)                                              \
    do {                                                             \
        gl16(Ks1 + (size_t)(t0) * 2048, &kt[bufi][(w * 64) * 8]);    \
        gl16(Ks2 + (size_t)(t0) * 2048, &kt[bufi][(512 + w * 64) * 8]); \
        gl16(Vs1 + (t0), &vt[bufi][(w * 64) * 8]);                   \
        gl16(Vs2 + (t0), &vt[bufi][(512 + w * 64) * 8]);             \
    } while (0)

    STAGE(0, 0);

    float m = -1e30f, l = 0.f;
    f32x4 zero4 = {0.f, 0.f, 0.f, 0.f};
    f32x4 oacc[4];
#pragma unroll
    for (int n = 0; n < 4; ++n) oacc[n] = zero4;
    const int cbase = (lane & 48) | (g << 2);
    __syncthreads();

    for (int tt = 0; tt < 8; ++tt) {
        const int cur = tt & 1;
        if (tt < 7) STAGE(cur ^ 1, (tt + 1) * 128);
        const char* kbuf = (const char*)&kt[cur][0];
        const char* vbuf = (const char*)&vt[cur][0];

        f32x4 sfT[8];
#pragma unroll
        for (int n = 0; n < 8; ++n) sfT[n] = zero4;
#pragma unroll
        for (int ks = 0; ks < 2; ++ks) {
            const short8 qf = ks ? qf1 : qf0;
#pragma unroll
            for (int n = 0; n < 8; ++n) {
                short8 kf = *(const short8*)(kbuf + swz((n * 16 + r) * 128 + ks * 64 + g * 16));
                sfT[n] = MFMA16(kf, qf, sfT[n]);
            }
        }
        float rm = -1e30f;
#pragma unroll
        for (int n = 0; n < 8; ++n)
            rm = fmaxf(rm, fmaxf(fmaxf(sfT[n][0], sfT[n][1]), fmaxf(sfT[n][2], sfT[n][3])));
        rm = fmaxf(rm, __shfl_xor(rm, 16, 64));
        rm = fmaxf(rm, __shfl_xor(rm, 32, 64));
        if (!__all(rm <= m + 8.f)) {
            float mn = fmaxf(m, rm);
            float cc = EXP2(m - mn);
            m = mn;
            l *= cc;
#pragma unroll
            for (int i = 0; i < 4; ++i) {
                float ci = __shfl(cc, cbase + i, 64);
#pragma unroll
                for (int n = 0; n < 4; ++n) oacc[n][i] *= ci;
            }
        }
        float rs = 0.f;
#pragma unroll
        for (int n = 0; n < 8; ++n)
#pragma unroll
            for (int i = 0; i < 4; ++i) {
                float p = EXP2(sfT[n][i] - m);
                sfT[n][i] = p;
                rs += p;
            }
        rs += __shfl_xor(rs, 16, 64);
        rs += __shfl_xor(rs, 32, 64);
        l += rs;
        u32 wpk[8][2];
#pragma unroll
        for (int n = 0; n < 8; ++n) {
            wpk[n][0] = cvtpk(sfT[n][0], sfT[n][1]);
            wpk[n][1] = cvtpk(sfT[n][2], sfT[n][3]);
        }
#pragma unroll
        for (int ks = 0; ks < 4; ++ks) {
            u32 a0 = wpk[2 * ks][0], a2 = wpk[2 * ks + 1][0];
            plswap(a0, a2);
            u32 a1 = wpk[2 * ks][1], a3 = wpk[2 * ks + 1][1];
            plswap(a1, a3);
            uint4 av;
            av.x = a0; av.y = a1; av.z = a2; av.w = a3;
            union { uint4 u; short8 s; } uc;
            uc.u = av;
            const short8 af = uc.s;
#pragma unroll
            for (int n = 0; n < 4; ++n) {
                short8 vf = *(const short8*)(vbuf + swzV((n * 16 + r) * 256 + ks * 64 + g * 16));
                oacc[n] = MFMA16(af, vf, oacc[n]);
            }
        }
        __syncthreads();
    }
#undef STAGE

#pragma unroll
    for (int i = 0; i < 4; ++i) {
        float li = 1.f / __shfl(l, cbase + i, 64);
        int orow = b * 1024 + qb * 128 + w * 16 + g * 4 + i;
#pragma unroll
        for (int n = 0; n < 4; ++n)
            Out[(size_t)orow * 1024 + h * 64 + n * 16 + r] = f2b(oacc[n][i] * li);
    }
}

// ---------------------------------------------------------------------------
// Fused residual + LayerNorm (R10 structure). QOUT=1: also emit per-row i8
// quantization of the LN output + scale (feeds the next i8 GEMM).
// ---------------------------------------------------------------------------
template <int QOUT>
__global__ __launch_bounds__(256) void ln_kernel(const u16* __restrict__ xin,
                                                 const u16* __restrict__ addin,
                                                 const float* __restrict__ gamma,
                                                 const float* __restrict__ beta,
                                                 u16* __restrict__ xbout,
                                                 i8* __restrict__ xq,
                                                 float* __restrict__ sx) {
    const int row = blockIdx.x, t = threadIdx.x;
    const size_t base = (size_t)row * 1024;
    ushort4 xu = *(const ushort4*)&xin[base + t * 4];
    ushort4 au = *(const ushort4*)&addin[base + t * 4];
    float v0 = b2f(xu.x) + b2f(au.x), v1 = b2f(xu.y) + b2f(au.y);
    float v2 = b2f(xu.z) + b2f(au.z), v3 = b2f(xu.w) + b2f(au.w);
    float s = v0 + v1 + v2 + v3;
    __shared__ float red[4];
    const int lane = t & 63, w = t >> 6;
#pragma unroll
    for (int off = 32; off; off >>= 1) s += __shfl_xor(s, off, 64);
    if (lane == 0) red[w] = s;
    __syncthreads();
    float mean = (red[0] + red[1] + red[2] + red[3]) * (1.f / 1024.f);
    __syncthreads();
    float d0 = v0 - mean, d1 = v1 - mean, d2 = v2 - mean, d3 = v3 - mean;
    float sq = d0 * d0 + d1 * d1 + d2 * d2 + d3 * d3;
#pragma unroll
    for (int off = 32; off; off >>= 1) sq += __shfl_xor(sq, off, 64);
    if (lane == 0) red[w] = sq;
    __syncthreads();
    float var = (red[0] + red[1] + red[2] + red[3]) * (1.f / 1024.f);
    float rstd = rsqrtf(var + 1e-5f);
    float4 gv = *(const float4*)&gamma[t * 4];
    float4 bv = *(const float4*)&beta[t * 4];
    float o0 = d0 * rstd * gv.x + bv.x;
    float o1 = d1 * rstd * gv.y + bv.y;
    float o2 = d2 * rstd * gv.z + bv.z;
    float o3 = d3 * rstd * gv.w + bv.w;
    ushort4 o;
    o.x = f2b(o0); o.y = f2b(o1); o.z = f2b(o2); o.w = f2b(o3);
    *(ushort4*)&xbout[base + t * 4] = o;
    if (QOUT) {
        float am = fmaxf(fmaxf(fabsf(o0), fabsf(o1)), fmaxf(fabsf(o2), fabsf(o3)));
#pragma unroll
        for (int off = 32; off; off >>= 1) am = fmaxf(am, __shfl_xor(am, off, 64));
        __syncthreads();
        if (lane == 0) red[w] = am;
        __syncthreads();
        float amax = fmaxf(fmaxf(red[0], red[1]), fmaxf(red[2], red[3]));
        float inv = (amax > 0.f) ? 127.f / amax : 0.f;
        u32 qw = pk4(qclamp(o0 * inv), qclamp(o1 * inv), qclamp(o2 * inv), qclamp(o3 * inv));
        *(u32*)&xq[base + t * 4] = qw;
        if (t == 0) sx[row] = (amax > 0.f) ? amax / 127.f : 0.f;
    }
}

// ---------------------------------------------------------------------------
extern "C" void kernel_launch(void* const* d_in, const int* in_sizes, int n_in,
                              void* d_out, int out_size, void* d_ws, size_t ws_size,
                              hipStream_t stream) {
    const float* x  = (const float*)d_in[0];
    const float* Wk = (const float*)d_in[1];
    const float* bk = (const float*)d_in[2];
    const float* Wv = (const float*)d_in[3];
    const float* bv = (const float*)d_in[4];
    const float* Wl = (const float*)d_in[5];
    const float* bl = (const float*)d_in[6];
    const float* g1 = (const float*)d_in[7];
    const float* b1 = (const float*)d_in[8];
    const float* g2 = (const float*)d_in[9];
    const float* b2 = (const float*)d_in[10];
    const float* Wo = (const float*)d_in[11];
    const float* bo = (const float*)d_in[12];

    char* ws = (char*)d_ws;
    u16* Wkvb = (u16*)ws;  ws += (size_t)4 * 2048 * 1024 * 2;   // 16 MB
    u16* Wlb  = (u16*)ws;  ws += (size_t)4 * 1024 * 1024 * 2;   //  8 MB
    u16* Wob  = (u16*)ws;  ws += (size_t)1024 * 1024 * 2;       //  2 MB
    u16* xb   = (u16*)ws;  ws += (size_t)4096 * 1024 * 2;       //  8 MB
    u16* KVb  = (u16*)ws;  ws += (size_t)4096 * 2048 * 2;       // 16 MB
    u16* VTb  = (u16*)ws;  ws += (size_t)4096 * 1024 * 2;       //  8 MB
    u16* tmpb = (u16*)ws;  ws += (size_t)4096 * 1024 * 2;       //  8 MB
    i8*  Wq   = (i8*)ws;   ws += (size_t)4 * 2048 * 1024;       //  8 MB
    i8*  Wlq  = (i8*)ws;   ws += (size_t)4 * 1024 * 1024;       //  4 MB
    i8*  Woq  = (i8*)ws;   ws += (size_t)1024 * 1024;           //  1 MB
    i8*  xq   = (i8*)ws;   ws += (size_t)4096 * 1024;           //  4 MB
    float* swf = (float*)ws; ws += (size_t)4 * 2048 * 4;        // 32 KB
    float* slf = (float*)ws; ws += (size_t)4 * 1024 * 4;        // 16 KB
    float* sof = (float*)ws; ws += (size_t)1024 * 4;            //  4 KB
    float* sxf = (float*)ws; ws += (size_t)4096 * 4;            // 16 KB

    pack_wkv_t<<<dim3(2, 32, 64), 256, 0, stream>>>(Wk, Wkvb, 0);
    pack_wkv_t<<<dim3(2, 32, 64), 256, 0, stream>>>(Wv, Wkvb, 1024);
    quant_rows<<<dim3(2048), 256, 0, stream>>>(Wkvb, Wq, swf);
    transpose_cvt<<<dim3(32, 32, 4), 256, 0, stream>>>(Wl, Wlb, 1024, 1024);
    quant_rows<<<dim3(1024), 256, 0, stream>>>(Wlb, Wlq, slf);
    transpose_cvt<<<dim3(32, 32, 1), 256, 0, stream>>>(Wo, Wob, 1024, 1024);
    quant_rows<<<dim3(256), 256, 0, stream>>>(Wob, Woq, sof);
    cvtq_row<<<dim3(1024), 256, 0, stream>>>(x, xb, xq, sxf);

    for (int l = 0; l < 4; ++l) {
        // KV: int8, tile 128x128 BK=128, grid 512 (region-mapped)
        gemm_kv_i8<<<dim3(512), 256, 0, stream>>>(
            xq, sxf, Wq + (size_t)l * 2048 * 1024, swf + l * 2048,
            bk + l * 1024, bv + l * 1024, KVb, VTb);
        attn_kernel<<<dim3(512), 512, 0, stream>>>(KVb, VTb, tmpb);
        ln_kernel<1><<<dim3(4096), 256, 0, stream>>>(
            xb, tmpb, g1 + l * 1024, b1 + l * 1024, xb, xq, sxf);
        // FFN: int8, tile 128x64 BK=128, grid 512 (region-mapped)
        gemm_i8<1><<<dim3(512), 256, 0, stream>>>(
            xq, sxf, Wlq + (size_t)l * 1024 * 1024, slf + l * 1024,
            bl + l * 1024, (void*)tmpb);
        ln_kernel<1><<<dim3(4096), 256, 0, stream>>>(
            xb, tmpb, g2 + l * 1024, b2 + l * 1024, xb, xq, sxf);
    }
    gemm_i8<2><<<dim3(512), 256, 0, stream>>>(
        xq, sxf, Woq, sof, bo, d_out);
}

// Round 19
// 418.921 us; speedup vs baseline: 1.2329x; 1.0078x over previous
//
#include <hip/hip_runtime.h>

typedef unsigned short u16;
typedef unsigned int u32;
typedef signed char i8;
typedef __attribute__((ext_vector_type(4))) float f32x4;
typedef __attribute__((ext_vector_type(4))) int i32x4;
typedef __attribute__((ext_vector_type(8))) short short8;

#if __has_builtin(__builtin_amdgcn_exp2f)
#define EXP2(x) __builtin_amdgcn_exp2f(x)
#else
#define EXP2(x) exp2f(x)
#endif

// 1/sqrt(64) * log2(e): K-proj pre-scale so softmax runs in exp2 domain
#define SCALEK 0.18033688011112042f

__device__ __forceinline__ u16 f2b(float f) {
    unsigned u = __float_as_uint(f);
    u += 0x7fff + ((u >> 16) & 1);
    return (u16)(u >> 16);
}
__device__ __forceinline__ float b2f(u16 v) {
    return __uint_as_float(((unsigned)v) << 16);
}
// XOR swizzle for 128-byte-row LDS tiles
__device__ __forceinline__ int swz(int byteoff) {
    return byteoff ^ (((byteoff >> 7) & 7) << 4);
}
// XOR swizzle for 256-byte-row LDS tiles
__device__ __forceinline__ int swzV(int byteoff) {
    return byteoff ^ (((byteoff >> 8) & 7) << 4);
}
// async global->LDS, 16B per lane; LDS dest must be wave-uniform base
__device__ __forceinline__ void gl16(const void* g, void* l) {
    __builtin_amdgcn_global_load_lds(
        (const __attribute__((address_space(1))) unsigned*)(g),
        (__attribute__((address_space(3))) unsigned*)(l), 16, 0, 0);
}
__device__ __forceinline__ u32 cvtpk(float lo, float hi) {
    u32 r;
    asm("v_cvt_pk_bf16_f32 %0, %1, %2" : "=v"(r) : "v"(lo), "v"(hi));
    return r;
}
// (a,b) -> rows: a'=[a0,a2,b0,b2], b'=[a1,a3,b1,b3]  (16-lane rows)
__device__ __forceinline__ void plswap(u32& a, u32& b) {
    asm("v_permlane32_swap_b32 %0, %1" : "+v"(a), "+v"(b));
    asm("v_permlane16_swap_b32 %0, %1" : "+v"(a), "+v"(b));
}
__device__ __forceinline__ void up8(uint4 u, float* v) {
    v[0] = b2f((u16)u.x); v[1] = b2f((u16)(u.x >> 16));
    v[2] = b2f((u16)u.y); v[3] = b2f((u16)(u.y >> 16));
    v[4] = b2f((u16)u.z); v[5] = b2f((u16)(u.z >> 16));
    v[6] = b2f((u16)u.w); v[7] = b2f((u16)(u.w >> 16));
}
__device__ __forceinline__ int qclamp(float v) {
    int q = __float2int_rn(v);
    return (q > 127) ? 127 : ((q < -127) ? -127 : q);
}
__device__ __forceinline__ u32 pk4(int a, int b, int c, int d) {
    return (u32)(unsigned char)a | ((u32)(unsigned char)b << 8) |
           ((u32)(unsigned char)c << 16) | ((u32)(unsigned char)d << 24);
}
#define MFMA16(a, b, c) __builtin_amdgcn_mfma_f32_16x16x32_bf16((a), (b), (c), 0, 0, 0)
#define MFMAI8(a, b, c) __builtin_amdgcn_mfma_i32_16x16x64_i8((a), (b), (c), 0, 0, 0)

// ---------------------------------------------------------------------------
// Weight packing: W[z][1024][64] -> out rows (voff + h*64 + k), cols d (bf16)
// ---------------------------------------------------------------------------
__global__ __launch_bounds__(256) void pack_wkv_t(const float* __restrict__ W,
                                                  u16* __restrict__ out, int voff) {
    __shared__ float tile[32][33];
    int z = blockIdx.z; int l = z >> 4, h = z & 15;
    const float* ip = W + (size_t)z * 1024 * 64;
    u16* op = out + (size_t)l * 2048 * 1024 + (size_t)(voff + h * 64) * 1024;
    int tx = threadIdx.x & 31, ty = threadIdx.x >> 5;
    int d0 = blockIdx.y * 32, k0 = blockIdx.x * 32;
#pragma unroll
    for (int j = 0; j < 32; j += 8)
        tile[ty + j][tx] = ip[(size_t)(d0 + ty + j) * 64 + k0 + tx];
    __syncthreads();
#pragma unroll
    for (int j = 0; j < 32; j += 8)
        op[(size_t)(k0 + ty + j) * 1024 + d0 + tx] = f2b(tile[tx][ty + j]);
}

__global__ __launch_bounds__(256) void transpose_cvt(const float* __restrict__ in,
                                                     u16* __restrict__ out, int R, int C) {
    __shared__ float tile[32][33];
    const float* ip = in + (size_t)blockIdx.z * R * C;
    u16* op = out + (size_t)blockIdx.z * R * C;
    int tx = threadIdx.x & 31, ty = threadIdx.x >> 5;
    int r0 = blockIdx.y * 32, c0 = blockIdx.x * 32;
#pragma unroll
    for (int j = 0; j < 32; j += 8)
        tile[ty + j][tx] = ip[(size_t)(r0 + ty + j) * C + c0 + tx];
    __syncthreads();
#pragma unroll
    for (int j = 0; j < 32; j += 8)
        op[(size_t)(c0 + ty + j) * R + r0 + tx] = f2b(tile[tx][ty + j]);
}

// ---------------------------------------------------------------------------
// Per-row i8 quantization of a bf16 matrix [Rows][1024] (one wave per row)
// ---------------------------------------------------------------------------
__global__ __launch_bounds__(256) void quant_rows(const u16* __restrict__ in,
                                                  i8* __restrict__ out,
                                                  float* __restrict__ scale) {
    const int t = threadIdx.x, lane = t & 63, w = t >> 6;
    const int row = blockIdx.x * 4 + w;
    const size_t base = (size_t)row * 1024 + lane * 16;
    uint4 v0 = *(const uint4*)&in[base];
    uint4 v1 = *(const uint4*)&in[base + 8];
    float v[16];
    up8(v0, v); up8(v1, v + 8);
    float amax = 0.f;
#pragma unroll
    for (int i = 0; i < 16; ++i) amax = fmaxf(amax, fabsf(v[i]));
#pragma unroll
    for (int off = 32; off; off >>= 1) amax = fmaxf(amax, __shfl_xor(amax, off, 64));
    const float inv = (amax > 0.f) ? 127.f / amax : 0.f;
    u32 q[4];
#pragma unroll
    for (int j = 0; j < 4; ++j)
        q[j] = pk4(qclamp(v[4 * j] * inv), qclamp(v[4 * j + 1] * inv),
                   qclamp(v[4 * j + 2] * inv), qclamp(v[4 * j + 3] * inv));
    uint4 qq = {q[0], q[1], q[2], q[3]};
    *(uint4*)&out[base] = qq;
    if (lane == 0) scale[row] = (amax > 0.f) ? amax / 127.f : 0.f;
}

// ---------------------------------------------------------------------------
// Initial x: f32 [4096][1024] -> bf16 xb + i8 xq + row scale (wave per row)
// ---------------------------------------------------------------------------
__global__ __launch_bounds__(256) void cvtq_row(const float* __restrict__ in,
                                                u16* __restrict__ outb,
                                                i8* __restrict__ outq,
                                                float* __restrict__ scale) {
    const int t = threadIdx.x, lane = t & 63, w = t >> 6;
    const int row = blockIdx.x * 4 + w;
    const size_t base = (size_t)row * 1024 + lane * 16;
    float v[16];
#pragma unroll
    for (int j = 0; j < 4; ++j) {
        float4 f = *(const float4*)&in[base + j * 4];
        v[4 * j] = f.x; v[4 * j + 1] = f.y; v[4 * j + 2] = f.z; v[4 * j + 3] = f.w;
    }
    u32 bw[8];
#pragma unroll
    for (int j = 0; j < 8; ++j) bw[j] = cvtpk(v[2 * j], v[2 * j + 1]);
    uint4 b0 = {bw[0], bw[1], bw[2], bw[3]};
    uint4 b1 = {bw[4], bw[5], bw[6], bw[7]};
    *(uint4*)&outb[base] = b0;
    *(uint4*)&outb[base + 8] = b1;
    float amax = 0.f;
#pragma unroll
    for (int i = 0; i < 16; ++i) amax = fmaxf(amax, fabsf(v[i]));
#pragma unroll
    for (int off = 32; off; off >>= 1) amax = fmaxf(amax, __shfl_xor(amax, off, 64));
    const float inv = (amax > 0.f) ? 127.f / amax : 0.f;
    u32 q[4];
#pragma unroll
    for (int j = 0; j < 4; ++j)
        q[j] = pk4(qclamp(v[4 * j] * inv), qclamp(v[4 * j + 1] * inv),
                   qclamp(v[4 * j + 2] * inv), qclamp(v[4 * j + 3] * inv));
    uint4 qq = {q[0], q[1], q[2], q[3]};
    *(uint4*)&outq[base] = qq;
    if (lane == 0) scale[row] = (amax > 0.f) ? amax / 127.f : 0.f;
}

// ---------------------------------------------------------------------------
// KV projection GEMM in int8 (R17 proven): C[4096][2048] = A_i8 @ B_i8^T,
// i32 accum, per-row scales. Tile 128x128, BK=128, 2-buf, region map.
// ---------------------------------------------------------------------------
__global__ __launch_bounds__(256) void gemm_kv_i8(const i8* __restrict__ A,
                                                  const float* __restrict__ sA,
                                                  const i8* __restrict__ B,
                                                  const float* __restrict__ sB,
                                                  const float* __restrict__ bias1,
                                                  const float* __restrict__ bias2,
                                                  u16* __restrict__ Cb,
                                                  u16* __restrict__ VTout) {
    constexpr int K = 1024, N = 2048;
    __shared__ __align__(16) i8 lA[2][8 * 128 * 16];
    __shared__ __align__(16) i8 lB[2][8 * 128 * 16];
    const int t = threadIdx.x;
    const int lane = t & 63, w = t >> 6;
    const int wr = w >> 1, wc = w & 1;
    const int g = lane >> 4, r = lane & 15;
    const int bid = blockIdx.x;
    const int rgn = bid & 7, idx = bid >> 3;
    const int by = (rgn >> 1) * 8 + (idx >> 3);
    const int bx = (rgn & 1) * 8 + (idx & 7);
    const int m0 = by * 128, n0 = bx * 128;

    const i8* sAp[4];
    const i8* sBp[4];
#pragma unroll
    for (int j = 0; j < 4; ++j) {
        int c = j * 256 + t;
        sAp[j] = A + (size_t)(m0 + (c & 127)) * K + (c >> 7) * 16;
        sBp[j] = B + (size_t)(n0 + (c & 127)) * K + (c >> 7) * 16;
    }

    i32x4 acc[4][4];
#pragma unroll
    for (int m = 0; m < 4; ++m)
#pragma unroll
        for (int n = 0; n < 4; ++n) acc[m][n] = (i32x4){0, 0, 0, 0};

#define GSTAGE(bufi, k0)                                                  \
    do {                                                                  \
        _Pragma("unroll") for (int j = 0; j < 4; ++j)                     \
            gl16(sAp[j] + (k0), &lA[bufi][(j * 256 + w * 64) * 16]);      \
        _Pragma("unroll") for (int j = 0; j < 4; ++j)                     \
            gl16(sBp[j] + (k0), &lB[bufi][(j * 256 + w * 64) * 16]);      \
    } while (0)

    GSTAGE(0, 0);
    __syncthreads();
    for (int kt = 0; kt < 8; ++kt) {
        const int cur = kt & 1;
        if (kt + 1 < 8) GSTAGE(cur ^ 1, (kt + 1) * 128);
#pragma unroll
        for (int ks = 0; ks < 2; ++ks) {
            i32x4 af[4], bf[4];
#pragma unroll
            for (int m = 0; m < 4; ++m)
                af[m] = *(const i32x4*)&lA[cur][((ks * 4 + g) * 128 + wr * 64 + m * 16 + r) * 16];
#pragma unroll
            for (int n = 0; n < 4; ++n)
                bf[n] = *(const i32x4*)&lB[cur][((ks * 4 + g) * 128 + wc * 64 + n * 16 + r) * 16];
#pragma unroll
            for (int m = 0; m < 4; ++m)
#pragma unroll
                for (int n = 0; n < 4; ++n)
                    acc[m][n] = MFMAI8(af[m], bf[n], acc[m][n]);
        }
        __syncthreads();
    }
#undef GSTAGE

#pragma unroll
    for (int m = 0; m < 4; ++m) {
        int row = m0 + wr * 64 + m * 16 + g * 4;
        float sx0 = sA[row], sx1 = sA[row + 1], sx2 = sA[row + 2], sx3 = sA[row + 3];
#pragma unroll
        for (int n = 0; n < 4; ++n) {
            int col = n0 + wc * 64 + n * 16 + r;
            float swv = sB[col];
            float bv_ = (col < 1024) ? bias1[col] : bias2[col - 1024];
            float sc = (col < 1024) ? SCALEK : 1.0f;
            ushort4 qv;
            qv.x = f2b(((float)acc[m][n][0] * sx0 * swv + bv_) * sc);
            qv.y = f2b(((float)acc[m][n][1] * sx1 * swv + bv_) * sc);
            qv.z = f2b(((float)acc[m][n][2] * sx2 * swv + bv_) * sc);
            qv.w = f2b(((float)acc[m][n][3] * sx3 * swv + bv_) * sc);
            Cb[(size_t)(row + 0) * N + col] = qv.x;
            Cb[(size_t)(row + 1) * N + col] = qv.y;
            Cb[(size_t)(row + 2) * N + col] = qv.z;
            Cb[(size_t)(row + 3) * N + col] = qv.w;
            if (col >= 1024) {
                int d = col - 1024, b_ = row >> 10, s = row & 1023;
                *(ushort4*)&VTout[(((size_t)(b_ * 16) + (d >> 6)) * 64 + (d & 63)) * 1024 + s] = qv;
            }
        }
    }
}

// ---------------------------------------------------------------------------
// Generic int8 GEMM, tile 128 x 64, BK=128, grid 512 (region map).
// EPI 1: bf16 out, bias + relu     EPI 2: fp32 out, bias
// ---------------------------------------------------------------------------
template <int EPI>
__global__ __launch_bounds__(256) void gemm_i8(const i8* __restrict__ A,
                                               const float* __restrict__ sA,
                                               const i8* __restrict__ B,
                                               const float* __restrict__ sB,
                                               const float* __restrict__ bias,
                                               void* __restrict__ Cv) {
    constexpr int K = 1024, N = 1024;
    __shared__ __align__(16) i8 lA[2][8 * 128 * 16];
    __shared__ __align__(16) i8 lB[2][8 * 64 * 16];
    const int t = threadIdx.x;
    const int lane = t & 63, w = t >> 6;
    const int wr = w >> 1, wc = w & 1;
    const int g = lane >> 4, r = lane & 15;
    const int bid = blockIdx.x;
    const int rgn = bid & 7, idx = bid >> 3;
    const int by = (rgn >> 1) * 8 + (idx >> 3);
    const int bx = (rgn & 1) * 8 + (idx & 7);
    const int m0 = by * 128, n0 = bx * 64;

    const i8* sAp[4];
    const i8* sBp[2];
#pragma unroll
    for (int j = 0; j < 4; ++j) {
        int c = j * 256 + t;
        sAp[j] = A + (size_t)(m0 + (c & 127)) * K + (c >> 7) * 16;
    }
#pragma unroll
    for (int j = 0; j < 2; ++j) {
        int c = j * 256 + t;
        sBp[j] = B + (size_t)(n0 + (c & 63)) * K + (c >> 6) * 16;
    }

    i32x4 acc[4][2];
#pragma unroll
    for (int m = 0; m < 4; ++m)
#pragma unroll
        for (int n = 0; n < 2; ++n) acc[m][n] = (i32x4){0, 0, 0, 0};

#define GSTAGE(bufi, k0)                                                  \
    do {                                                                  \
        _Pragma("unroll") for (int j = 0; j < 4; ++j)                     \
            gl16(sAp[j] + (k0), &lA[bufi][(j * 256 + w * 64) * 16]);      \
        _Pragma("unroll") for (int j = 0; j < 2; ++j)                     \
            gl16(sBp[j] + (k0), &lB[bufi][(j * 256 + w * 64) * 16]);      \
    } while (0)

    GSTAGE(0, 0);
    __syncthreads();
    for (int kt = 0; kt < 8; ++kt) {
        const int cur = kt & 1;
        if (kt + 1 < 8) GSTAGE(cur ^ 1, (kt + 1) * 128);
#pragma unroll
        for (int ks = 0; ks < 2; ++ks) {
            i32x4 af[4], bf[2];
#pragma unroll
            for (int m = 0; m < 4; ++m)
                af[m] = *(const i32x4*)&lA[cur][((ks * 4 + g) * 128 + wr * 64 + m * 16 + r) * 16];
#pragma unroll
            for (int n = 0; n < 2; ++n)
                bf[n] = *(const i32x4*)&lB[cur][((ks * 4 + g) * 64 + wc * 32 + n * 16 + r) * 16];
#pragma unroll
            for (int m = 0; m < 4; ++m)
#pragma unroll
                for (int n = 0; n < 2; ++n)
                    acc[m][n] = MFMAI8(af[m], bf[n], acc[m][n]);
        }
        __syncthreads();
    }
#undef GSTAGE

#pragma unroll
    for (int m = 0; m < 4; ++m) {
        int row = m0 + wr * 64 + m * 16 + g * 4;
        float sx0 = sA[row], sx1 = sA[row + 1], sx2 = sA[row + 2], sx3 = sA[row + 3];
#pragma unroll
        for (int n = 0; n < 2; ++n) {
            int col = n0 + wc * 32 + n * 16 + r;
            float swv = sB[col];
            float bv_ = bias[col];
            float v0 = (float)acc[m][n][0] * sx0 * swv + bv_;
            float v1 = (float)acc[m][n][1] * sx1 * swv + bv_;
            float v2 = (float)acc[m][n][2] * sx2 * swv + bv_;
            float v3 = (float)acc[m][n][3] * sx3 * swv + bv_;
            if (EPI == 1) {
                u16* Cb = (u16*)Cv;
                Cb[(size_t)(row + 0) * N + col] = f2b(fmaxf(v0, 0.f));
                Cb[(size_t)(row + 1) * N + col] = f2b(fmaxf(v1, 0.f));
                Cb[(size_t)(row + 2) * N + col] = f2b(fmaxf(v2, 0.f));
                Cb[(size_t)(row + 3) * N + col] = f2b(fmaxf(v3, 0.f));
            } else {
                float* Cf = (float*)Cv;
                Cf[(size_t)(row + 0) * N + col] = v0;
                Cf[(size_t)(row + 1) * N + col] = v1;
                Cf[(size_t)(row + 2) * N + col] = v2;
                Cf[(size_t)(row + 3) * N + col] = v3;
            }
        }
    }
}

// ---------------------------------------------------------------------------
// Flash attention, swapped-QK^T in-register softmax. WIDE blocks: 16 waves
// (1024 threads) x 16 q-rows = 256 q-rows/block, grid 256 (1/CU). Each
// (b,h)'s KV tiles staged by 4 blocks instead of 8 -> staging traffic
// halved (65 MB/dispatch). Per-wave inner loop identical to R18.
// ---------------------------------------------------------------------------
__global__ __launch_bounds__(1024) void attn_kernel(const u16* __restrict__ KV,
                                                    const u16* __restrict__ VT,
                                                    u16* __restrict__ Out) {
    __shared__ __align__(16) u16 kt[2][1024 * 8];   // [key 0..127][d 0..63]
    __shared__ __align__(16) u16 vt[2][1024 * 8];   // [d 0..63][key 0..127]
    const int t = threadIdx.x;
    const int lane = t & 63, w = t >> 6;            // 16 waves
    const int g = lane >> 4, r = lane & 15;
    const int d0 = blockIdx.x;
    const int hi = d0 & 7;                          // XCD
    const int qb = (d0 >> 3) & 3;                   // 4 q-blocks of 256 rows
    const int mid = d0 >> 5;                        // 8 per XCD
    const int bh = hi * 8 + mid;
    const int h = bh & 15, b = bh >> 4;
    const u16* Kbase = KV + (size_t)b * 1024 * 2048 + h * 64;
    const u16* Vbase = Kbase + 1024;
    const u16* VTbase = VT + ((size_t)(b * 16 + h)) * 64 * 1024;

    // loop-invariant Q fragments: q-row = qb*256 + w*16 + r
    const int qrow = qb * 256 + w * 16 + r;
    const short8 qf0 = *(const short8*)&Kbase[(size_t)qrow * 2048 + g * 8];
    const short8 qf1 = *(const short8*)&Kbase[(size_t)qrow * 2048 + 32 + g * 8];

    // staging: 1024 chunks per matrix per tile, exactly 1 per thread
    const int krow = t >> 3;                        // 0..127
    const int kcol = ((((t & 7) * 16) ^ ((krow & 7) << 4)) >> 1);
    const u16* Ks = Vbase + (size_t)krow * 2048 + kcol;
    const int vrow = t >> 4;                        // 0..63
    const int vcol = ((((t & 15) * 16) ^ ((vrow & 7) << 4)) >> 1);
    const u16* Vs = VTbase + (size_t)vrow * 1024 + vcol;

#define STAGE(bufi, t0)                                            \
    do {                                                           \
        gl16(Ks + (size_t)(t0) * 2048, &kt[bufi][(w * 64) * 8]);   \
        gl16(Vs + (t0), &vt[bufi][(w * 64) * 8]);                  \
    } while (0)

    STAGE(0, 0);

    float m = -1e30f, l = 0.f;
    f32x4 zero4 = {0.f, 0.f, 0.f, 0.f};
    f32x4 oacc[4];
#pragma unroll
    for (int n = 0; n < 4; ++n) oacc[n] = zero4;
    const int cbase = (lane & 48) | (g << 2);
    __syncthreads();

    for (int tt = 0; tt < 8; ++tt) {
        const int cur = tt & 1;
        if (tt < 7) STAGE(cur ^ 1, (tt + 1) * 128);
        const char* kbuf = (const char*)&kt[cur][0];
        const char* vbuf = (const char*)&vt[cur][0];

        f32x4 sfT[8];
#pragma unroll
        for (int n = 0; n < 8; ++n) sfT[n] = zero4;
#pragma unroll
        for (int ks = 0; ks < 2; ++ks) {
            const short8 qf = ks ? qf1 : qf0;
#pragma unroll
            for (int n = 0; n < 8; ++n) {
                short8 kf = *(const short8*)(kbuf + swz((n * 16 + r) * 128 + ks * 64 + g * 16));
                sfT[n] = MFMA16(kf, qf, sfT[n]);
            }
        }
        float rm = -1e30f;
#pragma unroll
        for (int n = 0; n < 8; ++n)
            rm = fmaxf(rm, fmaxf(fmaxf(sfT[n][0], sfT[n][1]), fmaxf(sfT[n][2], sfT[n][3])));
        rm = fmaxf(rm, __shfl_xor(rm, 16, 64));
        rm = fmaxf(rm, __shfl_xor(rm, 32, 64));
        if (!__all(rm <= m + 8.f)) {
            float mn = fmaxf(m, rm);
            float cc = EXP2(m - mn);
            m = mn;
            l *= cc;
#pragma unroll
            for (int i = 0; i < 4; ++i) {
                float ci = __shfl(cc, cbase + i, 64);
#pragma unroll
                for (int n = 0; n < 4; ++n) oacc[n][i] *= ci;
            }
        }
        float rs = 0.f;
#pragma unroll
        for (int n = 0; n < 8; ++n)
#pragma unroll
            for (int i = 0; i < 4; ++i) {
                float p = EXP2(sfT[n][i] - m);
                sfT[n][i] = p;
                rs += p;
            }
        rs += __shfl_xor(rs, 16, 64);
        rs += __shfl_xor(rs, 32, 64);
        l += rs;
        u32 wpk[8][2];
#pragma unroll
        for (int n = 0; n < 8; ++n) {
            wpk[n][0] = cvtpk(sfT[n][0], sfT[n][1]);
            wpk[n][1] = cvtpk(sfT[n][2], sfT[n][3]);
        }
#pragma unroll
        for (int ks = 0; ks < 4; ++ks) {
            u32 a0 = wpk[2 * ks][0], a2 = wpk[2 * ks + 1][0];
            plswap(a0, a2);
            u32 a1 = wpk[2 * ks][1], a3 = wpk[2 * ks + 1][1];
            plswap(a1, a3);
            uint4 av;
            av.x = a0; av.y = a1; av.z = a2; av.w = a3;
            union { uint4 u; short8 s; } uc;
            uc.u = av;
            const short8 af = uc.s;
#pragma unroll
            for (int n = 0; n < 4; ++n) {
                short8 vf = *(const short8*)(vbuf + swzV((n * 16 + r) * 256 + ks * 64 + g * 16));
                oacc[n] = MFMA16(af, vf, oacc[n]);
            }
        }
        __syncthreads();
    }
#undef STAGE

#pragma unroll
    for (int i = 0; i < 4; ++i) {
        float li = 1.f / __shfl(l, cbase + i, 64);
        int orow = b * 1024 + qb * 256 + w * 16 + g * 4 + i;
#pragma unroll
        for (int n = 0; n < 4; ++n)
            Out[(size_t)orow * 1024 + h * 64 + n * 16 + r] = f2b(oacc[n][i] * li);
    }
}

// ---------------------------------------------------------------------------
// Fused residual + LayerNorm (R18 version). QOUT=1: also emit per-row i8
// quantization of the LN output + scale.
// ---------------------------------------------------------------------------
template <int QOUT>
__global__ __launch_bounds__(256) void ln_kernel(const u16* __restrict__ xin,
                                                 const u16* __restrict__ addin,
                                                 const float* __restrict__ gamma,
                                                 const float* __restrict__ beta,
                                                 u16* __restrict__ xbout,
                                                 i8* __restrict__ xq,
                                                 float* __restrict__ sx) {
    const int row = blockIdx.x, t = threadIdx.x;
    const size_t base = (size_t)row * 1024;
    ushort4 xu = *(const ushort4*)&xin[base + t * 4];
    ushort4 au = *(const ushort4*)&addin[base + t * 4];
    float v0 = b2f(xu.x) + b2f(au.x), v1 = b2f(xu.y) + b2f(au.y);
    float v2 = b2f(xu.z) + b2f(au.z), v3 = b2f(xu.w) + b2f(au.w);
    float s = v0 + v1 + v2 + v3;
    __shared__ float red[4];
    const int lane = t & 63, w = t >> 6;
#pragma unroll
    for (int off = 32; off; off >>= 1) s += __shfl_xor(s, off, 64);
    if (lane == 0) red[w] = s;
    __syncthreads();
    float mean = (red[0] + red[1] + red[2] + red[3]) * (1.f / 1024.f);
    __syncthreads();
    float d0 = v0 - mean, d1 = v1 - mean, d2 = v2 - mean, d3 = v3 - mean;
    float sq = d0 * d0 + d1 * d1 + d2 * d2 + d3 * d3;
#pragma unroll
    for (int off = 32; off; off >>= 1) sq += __shfl_xor(sq, off, 64);
    if (lane == 0) red[w] = sq;
    __syncthreads();
    float var = (red[0] + red[1] + red[2] + red[3]) * (1.f / 1024.f);
    float rstd = rsqrtf(var + 1e-5f);
    float4 gv = *(const float4*)&gamma[t * 4];
    float4 bv = *(const float4*)&beta[t * 4];
    float o0 = d0 * rstd * gv.x + bv.x;
    float o1 = d1 * rstd * gv.y + bv.y;
    float o2 = d2 * rstd * gv.z + bv.z;
    float o3 = d3 * rstd * gv.w + bv.w;
    ushort4 o;
    o.x = f2b(o0); o.y = f2b(o1); o.z = f2b(o2); o.w = f2b(o3);
    *(ushort4*)&xbout[base + t * 4] = o;
    if (QOUT) {
        float am = fmaxf(fmaxf(fabsf(o0), fabsf(o1)), fmaxf(fabsf(o2), fabsf(o3)));
#pragma unroll
        for (int off = 32; off; off >>= 1) am = fmaxf(am, __shfl_xor(am, off, 64));
        __syncthreads();
        if (lane == 0) red[w] = am;
        __syncthreads();
        float amax = fmaxf(fmaxf(red[0], red[1]), fmaxf(red[2], red[3]));
        float inv = (amax > 0.f) ? 127.f / amax : 0.f;
        u32 qw = pk4(qclamp(o0 * inv), qclamp(o1 * inv), qclamp(o2 * inv), qclamp(o3 * inv));
        *(u32*)&xq[base + t * 4] = qw;
        if (t == 0) sx[row] = (amax > 0.f) ? amax / 127.f : 0.f;
    }
}

// ---------------------------------------------------------------------------
extern "C" void kernel_launch(void* const* d_in, const int* in_sizes, int n_in,
                              void* d_out, int out_size, void* d_ws, size_t ws_size,
                              hipStream_t stream) {
    const float* x  = (const float*)d_in[0];
    const float* Wk = (const float*)d_in[1];
    const float* bk = (const float*)d_in[2];
    const float* Wv = (const float*)d_in[3];
    const float* bv = (const float*)d_in[4];
    const float* Wl = (const float*)d_in[5];
    const float* bl = (const float*)d_in[6];
    const float* g1 = (const float*)d_in[7];
    const float* b1 = (const float*)d_in[8];
    const float* g2 = (const float*)d_in[9];
    const float* b2 = (const float*)d_in[10];
    const float* Wo = (const float*)d_in[11];
    const float* bo = (const float*)d_in[12];

    char* ws = (char*)d_ws;
    u16* Wkvb = (u16*)ws;  ws += (size_t)4 * 2048 * 1024 * 2;   // 16 MB
    u16* Wlb  = (u16*)ws;  ws += (size_t)4 * 1024 * 1024 * 2;   //  8 MB
    u16* Wob  = (u16*)ws;  ws += (size_t)1024 * 1024 * 2;       //  2 MB
    u16* xb   = (u16*)ws;  ws += (size_t)4096 * 1024 * 2;       //  8 MB
    u16* KVb  = (u16*)ws;  ws += (size_t)4096 * 2048 * 2;       // 16 MB
    u16* VTb  = (u16*)ws;  ws += (size_t)4096 * 1024 * 2;       //  8 MB
    u16* tmpb = (u16*)ws;  ws += (size_t)4096 * 1024 * 2;       //  8 MB
    i8*  Wq   = (i8*)ws;   ws += (size_t)4 * 2048 * 1024;       //  8 MB
    i8*  Wlq  = (i8*)ws;   ws += (size_t)4 * 1024 * 1024;       //  4 MB
    i8*  Woq  = (i8*)ws;   ws += (size_t)1024 * 1024;           //  1 MB
    i8*  xq   = (i8*)ws;   ws += (size_t)4096 * 1024;           //  4 MB
    float* swf = (float*)ws; ws += (size_t)4 * 2048 * 4;        // 32 KB
    float* slf = (float*)ws; ws += (size_t)4 * 1024 * 4;        // 16 KB
    float* sof = (float*)ws; ws += (size_t)1024 * 4;            //  4 KB
    float* sxf = (float*)ws; ws += (size_t)4096 * 4;            // 16 KB

    pack_wkv_t<<<dim3(2, 32, 64), 256, 0, stream>>>(Wk, Wkvb, 0);
    pack_wkv_t<<<dim3(2, 32, 64), 256, 0, stream>>>(Wv, Wkvb, 1024);
    quant_rows<<<dim3(2048), 256, 0, stream>>>(Wkvb, Wq, swf);
    transpose_cvt<<<dim3(32, 32, 4), 256, 0, stream>>>(Wl, Wlb, 1024, 1024);
    quant_rows<<<dim3(1024), 256, 0, stream>>>(Wlb, Wlq, slf);
    transpose_cvt<<<dim3(32, 32, 1), 256, 0, stream>>>(Wo, Wob, 1024, 1024);
    quant_rows<<<dim3(256), 256, 0, stream>>>(Wob, Woq, sof);
    cvtq_row<<<dim3(1024), 256, 0, stream>>>(x, xb, xq, sxf);

    for (int l = 0; l < 4; ++l) {
        // KV: int8, tile 128x128 BK=128, grid 512 (region-mapped)
        gemm_kv_i8<<<dim3(512), 256, 0, stream>>>(
            xq, sxf, Wq + (size_t)l * 2048 * 1024, swf + l * 2048,
            bk + l * 1024, bv + l * 1024, KVb, VTb);
        // attention: wide blocks (256 q-rows), grid 256, 1024 threads
        attn_kernel<<<dim3(256), 1024, 0, stream>>>(KVb, VTb, tmpb);
        ln_kernel<1><<<dim3(4096), 256, 0, stream>>>(
            xb, tmpb, g1 + l * 1024, b1 + l * 1024, xb, xq, sxf);
        // FFN: int8, tile 128x64 BK=128, grid 512 (region-mapped)
        gemm_i8<1><<<dim3(512), 256, 0, stream>>>(
            xq, sxf, Wlq + (size_t)l * 1024 * 1024, slf + l * 1024,
            bl + l * 1024, (void*)tmpb);
        ln_kernel<1><<<dim3(4096), 256, 0, stream>>>(
            xb, tmpb, g2 + l * 1024, b2 + l * 1024, xb, xq, sxf);
    }
    gemm_i8<2><<<dim3(512), 256, 0, stream>>>(
        xq, sxf, Woq, sof, bo, d_out);
}